// Round 2
// baseline (629.287 us; speedup 1.0000x reference)
//
#include <hip/hip_runtime.h>
#include <hip/hip_bf16.h>

typedef __bf16 bf16;
typedef __bf16 bf16x4 __attribute__((ext_vector_type(4)));
typedef __bf16 bf16x8 __attribute__((ext_vector_type(8)));
typedef float f32x4 __attribute__((ext_vector_type(4)));

#define AS1 __attribute__((address_space(1)))
#define AS3 __attribute__((address_space(3)))

// Async global->LDS, 16B per lane. LDS dest is wave-uniform base + lane*16.
__device__ __forceinline__ void load_lds16(const void* g, void* l) {
  __builtin_amdgcn_global_load_lds((AS1 void*)g, (AS3 void*)l, 16, 0, 0);
}

// ---------------------------------------------------------------------------
// fp32 -> bf16 conversion (inputs are float32 per the reference)
// ---------------------------------------------------------------------------
__global__ void f2b(const float* __restrict__ in, bf16* __restrict__ out, int n) {
  int i = (blockIdx.x * 256 + threadIdx.x) * 4;
  if (i < n) {
    float4 v = *(const float4*)(in + i);
    bf16x4 o = {(bf16)v.x, (bf16)v.y, (bf16)v.z, (bf16)v.w};
    *(bf16x4*)(out + i) = o;
  }
}

// ---------------------------------------------------------------------------
// GEMM: C[M][N] = A[M][K] * Bw[N][K]^T   (bf16 in, fp32 accumulate)
// 128x128 tile, BK=32, 4 waves (2x2 of 64x64), 16x16x32 bf16 MFMA.
// ---------------------------------------------------------------------------
template <typename OutT>
__global__ __launch_bounds__(256) void gemm_bt(const bf16* __restrict__ A,
                                               const bf16* __restrict__ Bw,
                                               OutT* __restrict__ C,
                                               int M, int N, int K) {
  __shared__ bf16 As[128][32];
  __shared__ bf16 Bs[128][32];
  const int t = threadIdx.x;
  const int wave = t >> 6;
  const int lane = t & 63;
  const int qd = lane >> 4;   // quad 0..3
  const int ln = lane & 15;
  const int wm = (wave >> 1) * 64;
  const int wn = (wave & 1) * 64;
  const size_t bm = (size_t)blockIdx.y * 128;
  const size_t bn = (size_t)blockIdx.x * 128;

  const bf16* Ab = A + bm * (size_t)K;
  const bf16* Bb = Bw + bn * (size_t)K;

  f32x4 acc[4][4] = {};

  for (int k0 = 0; k0 < K; k0 += 32) {
#pragma unroll
    for (int i = 0; i < 2; i++) {
      int e = i * 256 + t;
      // tile row = e>>2 (4 x 16B segments per 64B row), col = (e&3)*8 elems
      load_lds16(Ab + (size_t)(e >> 2) * K + k0 + (e & 3) * 8,
                 (char*)As + i * 4096 + wave * 1024);
      load_lds16(Bb + (size_t)(e >> 2) * K + k0 + (e & 3) * 8,
                 (char*)Bs + i * 4096 + wave * 1024);
    }
    __syncthreads();

    bf16x8 af[4], bfr[4];
#pragma unroll
    for (int i = 0; i < 4; i++)
      af[i] = *(const bf16x8*)&As[wm + i * 16 + ln][qd * 8];
#pragma unroll
    for (int j = 0; j < 4; j++)
      bfr[j] = *(const bf16x8*)&Bs[wn + j * 16 + ln][qd * 8];
#pragma unroll
    for (int i = 0; i < 4; i++)
#pragma unroll
      for (int j = 0; j < 4; j++)
        acc[i][j] = __builtin_amdgcn_mfma_f32_16x16x32_bf16(af[i], bfr[j],
                                                            acc[i][j], 0, 0, 0);
    __syncthreads();
  }

  // Epilogue: C/D layout col = lane&15, row = quad*4 + reg
#pragma unroll
  for (int i = 0; i < 4; i++)
#pragma unroll
    for (int j = 0; j < 4; j++)
#pragma unroll
      for (int r = 0; r < 4; r++) {
        size_t row = bm + wm + i * 16 + qd * 4 + r;
        size_t col = bn + wn + j * 16 + ln;
        C[row * N + col] = (OutT)acc[i][j][r];
      }
}

// ---------------------------------------------------------------------------
// RoPE + permute Q: (B,S,32,64) -> (B,32,S,64).  freqs are fp32.
// ---------------------------------------------------------------------------
__global__ void rope_q(const bf16* __restrict__ Qp, const float* __restrict__ fc,
                       const float* __restrict__ fs, bf16* __restrict__ Qr) {
  int idx = blockIdx.x * 256 + threadIdx.x;  // pair index, 2*2048*32*32 total
  int i = idx & 31;
  int h = (idx >> 5) & 31;
  int s = (idx >> 10) & 2047;
  int b = idx >> 21;
  size_t src = ((size_t)(b * 2048 + s) * 32 + h) * 64 + 2 * i;
  float tr = (float)Qp[src], ti = (float)Qp[src + 1];
  float c = fc[s * 32 + i], sn = fs[s * 32 + i];
  size_t dst = ((size_t)(b * 32 + h) * 2048 + s) * 64 + 2 * i;
  Qr[dst] = (bf16)(tr * c - ti * sn);
  Qr[dst + 1] = (bf16)(tr * sn + ti * c);
}

// RoPE + permute K: (B,S,8,64) -> (B,8,S,64)
__global__ void rope_k(const bf16* __restrict__ Kp, const float* __restrict__ fc,
                       const float* __restrict__ fs, bf16* __restrict__ Kr) {
  int idx = blockIdx.x * 256 + threadIdx.x;  // 2*2048*8*32 total
  int i = idx & 31;
  int h = (idx >> 5) & 7;
  int s = (idx >> 8) & 2047;
  int b = idx >> 19;
  size_t src = ((size_t)(b * 2048 + s) * 8 + h) * 64 + 2 * i;
  float tr = (float)Kp[src], ti = (float)Kp[src + 1];
  float c = fc[s * 32 + i], sn = fs[s * 32 + i];
  size_t dst = ((size_t)(b * 8 + h) * 2048 + s) * 64 + 2 * i;
  Kr[dst] = (bf16)(tr * c - ti * sn);
  Kr[dst + 1] = (bf16)(tr * sn + ti * c);
}

// V transpose: (B,S,8,64) -> (B,8,64,S)  via LDS tile
__global__ void vtrans(const bf16* __restrict__ Vp, bf16* __restrict__ Vt) {
  __shared__ bf16 tile[64][65];
  int b = blockIdx.y >> 3, kh = blockIdx.y & 7;
  int s0 = blockIdx.x * 64;
#pragma unroll
  for (int i = 0; i < 16; i++) {
    int e = i * 256 + threadIdx.x;
    int r = e >> 6, c = e & 63;
    tile[r][c] = Vp[((size_t)(b * 2048 + s0 + r) * 8 + kh) * 64 + c];
  }
  __syncthreads();
#pragma unroll
  for (int i = 0; i < 16; i++) {
    int e = i * 256 + threadIdx.x;
    int d = e >> 6, s = e & 63;
    Vt[((size_t)(b * 8 + kh) * 64 + d) * 2048 + s0 + s] = tile[s][d];
  }
}

// ---------------------------------------------------------------------------
// Flash attention, causal. Q:(B,32,S,64)  K:(B,8,S,64)  Vt:(B,8,64,S)
// Output O:(B,S,32,64). One block = 128 q rows of one (b,h). 4 waves.
// ---------------------------------------------------------------------------
__global__ __launch_bounds__(256) void attn_fwd(const bf16* __restrict__ Q,
                                                const bf16* __restrict__ Kg,
                                                const bf16* __restrict__ Vg,
                                                bf16* __restrict__ O) {
  __shared__ bf16 Qs[128][64];
  __shared__ bf16 Ks[64][64];
  __shared__ bf16 Vs[64][64];   // [d][k]
  __shared__ bf16 Ps[128][64];
  const int t = threadIdx.x;
  const int wave = t >> 6, lane = t & 63, qd = lane >> 4, ln = lane & 15;
  const int qt = blockIdx.x;
  const int bh = blockIdx.y;
  const int b = bh >> 5, h = bh & 31, kh = h >> 2;
  const bf16* Qb = Q + ((size_t)(b * 32 + h) * 2048 + qt * 128) * 64;
  const bf16* Kb = Kg + (size_t)(b * 8 + kh) * 2048 * 64;
  const bf16* Vb = Vg + (size_t)(b * 8 + kh) * 64 * 2048;

  // stage Q tile (128x64 = 16KB = 4 issues of 256 lanes x 16B)
#pragma unroll
  for (int i = 0; i < 4; i++) {
    int e = i * 256 + t;
    load_lds16(Qb + (size_t)(e >> 3) * 64 + (e & 7) * 8,
               (char*)Qs + i * 4096 + wave * 1024);
  }

  f32x4 o_acc[2][4] = {};
  float m_st[2][4], l_st[2][4];
#pragma unroll
  for (int mi = 0; mi < 2; mi++)
#pragma unroll
    for (int r = 0; r < 4; r++) {
      m_st[mi][r] = -1e30f;
      l_st[mi][r] = 0.f;
    }

  const int q_row_base = qt * 128 + wave * 32;
  const int nkb = 2 * qt + 2;  // causal: k blocks 0 .. 2*qt+1

  for (int kb = 0; kb < nkb; kb++) {
    __syncthreads();  // prev iteration's LDS reads complete
#pragma unroll
    for (int i = 0; i < 2; i++) {
      int e = i * 256 + t;
      load_lds16(Kb + (size_t)(kb * 64 + (e >> 3)) * 64 + (e & 7) * 8,
                 (char*)Ks + i * 4096 + wave * 1024);
      load_lds16(Vb + (size_t)(e >> 3) * 2048 + kb * 64 + (e & 7) * 8,
                 (char*)Vs + i * 4096 + wave * 1024);
    }
    __syncthreads();  // staging (incl. Q on first iter) visible

    // S = Q K^T, per wave: 32 q rows x 64 k cols
    f32x4 s_acc[2][4] = {};
#pragma unroll
    for (int kk = 0; kk < 2; kk++) {
      bf16x8 aq[2], bk[4];
#pragma unroll
      for (int mi = 0; mi < 2; mi++)
        aq[mi] = *(const bf16x8*)&Qs[wave * 32 + mi * 16 + ln][kk * 32 + qd * 8];
#pragma unroll
      for (int j = 0; j < 4; j++)
        bk[j] = *(const bf16x8*)&Ks[j * 16 + ln][kk * 32 + qd * 8];
#pragma unroll
      for (int mi = 0; mi < 2; mi++)
#pragma unroll
        for (int j = 0; j < 4; j++)
          s_acc[mi][j] = __builtin_amdgcn_mfma_f32_16x16x32_bf16(
              aq[mi], bk[j], s_acc[mi][j], 0, 0, 0);
    }

    // online softmax per q-row (row = quad*4 + r in each 16-tile)
#pragma unroll
    for (int mi = 0; mi < 2; mi++) {
#pragma unroll
      for (int r = 0; r < 4; r++) {
        int q_glob = q_row_base + mi * 16 + qd * 4 + r;
        float sv[4];
        float mx = -1e30f;
#pragma unroll
        for (int j = 0; j < 4; j++) {
          int k_glob = kb * 64 + j * 16 + ln;
          float s = s_acc[mi][j][r] * 0.125f;
          if (k_glob > q_glob) s += -32768.0f;  // matches reference mask add
          sv[j] = s;
          mx = fmaxf(mx, s);
        }
#pragma unroll
        for (int off = 1; off < 16; off <<= 1)
          mx = fmaxf(mx, __shfl_xor(mx, off));
        float mnew = fmaxf(m_st[mi][r], mx);
        float alpha = __expf(m_st[mi][r] - mnew);
        m_st[mi][r] = mnew;
        float rs = 0.f;
#pragma unroll
        for (int j = 0; j < 4; j++) {
          float pv = __expf(sv[j] - mnew);
          rs += pv;
          Ps[wave * 32 + mi * 16 + qd * 4 + r][j * 16 + ln] = (bf16)pv;
        }
#pragma unroll
        for (int off = 1; off < 16; off <<= 1) rs += __shfl_xor(rs, off);
        l_st[mi][r] = l_st[mi][r] * alpha + rs;
#pragma unroll
        for (int dj = 0; dj < 4; dj++) o_acc[mi][dj][r] *= alpha;
      }
    }
    __syncthreads();  // P writes visible

    // O += P @ V : contraction over 64 keys (2 MFMA k-steps)
#pragma unroll
    for (int kk = 0; kk < 2; kk++) {
      bf16x8 ap[2], bv[4];
#pragma unroll
      for (int mi = 0; mi < 2; mi++)
        ap[mi] = *(const bf16x8*)&Ps[wave * 32 + mi * 16 + ln][kk * 32 + qd * 8];
#pragma unroll
      for (int dj = 0; dj < 4; dj++)
        bv[dj] = *(const bf16x8*)&Vs[dj * 16 + ln][kk * 32 + qd * 8];
#pragma unroll
      for (int mi = 0; mi < 2; mi++)
#pragma unroll
        for (int dj = 0; dj < 4; dj++)
          o_acc[mi][dj] = __builtin_amdgcn_mfma_f32_16x16x32_bf16(
              ap[mi], bv[dj], o_acc[mi][dj], 0, 0, 0);
    }
  }

  // epilogue: O[(b,s,h,d)] = o/l
#pragma unroll
  for (int mi = 0; mi < 2; mi++)
#pragma unroll
    for (int r = 0; r < 4; r++) {
      int s_idx = qt * 128 + wave * 32 + mi * 16 + qd * 4 + r;
      float inv = 1.f / l_st[mi][r];
#pragma unroll
      for (int dj = 0; dj < 4; dj++) {
        int d = dj * 16 + ln;
        O[((size_t)(b * 2048 + s_idx) * 32 + h) * 64 + d] =
            (bf16)(o_acc[mi][dj][r] * inv);
      }
    }
}

// ---------------------------------------------------------------------------
extern "C" void kernel_launch(void* const* d_in, const int* in_sizes, int n_in,
                              void* d_out, int out_size, void* d_ws,
                              size_t ws_size, hipStream_t stream) {
  const float* x = (const float*)d_in[0];
  const float* fc = (const float*)d_in[1];
  const float* fs = (const float*)d_in[2];
  const float* wq = (const float*)d_in[3];
  const float* wk = (const float*)d_in[4];
  const float* wv = (const float*)d_in[5];
  const float* wo = (const float*)d_in[6];
  float* out = (float*)d_out;

  char* ws = (char*)d_ws;
  const size_t MB = (size_t)1 << 20;
  bf16* xb  = (bf16*)(ws + 0 * MB);   // 16 MB (4096,2048)
  bf16* wqb = (bf16*)(ws + 16 * MB);  // 8 MB  (2048,2048)
  bf16* wkb = (bf16*)(ws + 24 * MB);  // 2 MB  (512,2048)
  bf16* wvb = (bf16*)(ws + 26 * MB);  // 2 MB  (512,2048)
  bf16* wob = (bf16*)(ws + 28 * MB);  // 8 MB  (2048,2048)
  bf16* Qp  = (bf16*)(ws + 36 * MB);  // 16 MB (B,S,32,64)
  bf16* Kp  = (bf16*)(ws + 52 * MB);  // 4 MB  (B,S,8,64)
  bf16* Vp  = (bf16*)(ws + 56 * MB);  // 4 MB  (B,S,8,64)
  bf16* Qr  = (bf16*)(ws + 60 * MB);  // 16 MB (B,32,S,64)
  bf16* Kr  = (bf16*)(ws + 76 * MB);  // 4 MB  (B,8,S,64)
  bf16* Vt  = (bf16*)(ws + 80 * MB);  // 4 MB  (B,8,64,S)
  bf16* Oa  = (bf16*)(ws + 36 * MB);  // 16 MB (B,S,32,64) — reuses Qp (dead)

  dim3 blk(256);
  // fp32 -> bf16 conversions
  f2b<<<8192, blk, 0, stream>>>(x, xb, 8388608);
  f2b<<<4096, blk, 0, stream>>>(wq, wqb, 4194304);
  f2b<<<1024, blk, 0, stream>>>(wk, wkb, 1048576);
  f2b<<<1024, blk, 0, stream>>>(wv, wvb, 1048576);
  f2b<<<4096, blk, 0, stream>>>(wo, wob, 4194304);

  gemm_bt<bf16><<<dim3(16, 32), blk, 0, stream>>>(xb, wqb, Qp, 4096, 2048, 2048);
  gemm_bt<bf16><<<dim3(4, 32), blk, 0, stream>>>(xb, wkb, Kp, 4096, 512, 2048);
  gemm_bt<bf16><<<dim3(4, 32), blk, 0, stream>>>(xb, wvb, Vp, 4096, 512, 2048);
  rope_q<<<16384, blk, 0, stream>>>(Qp, fc, fs, Qr);
  rope_k<<<4096, blk, 0, stream>>>(Kp, fc, fs, Kr);
  vtrans<<<dim3(32, 16), blk, 0, stream>>>(Vp, Vt);
  attn_fwd<<<dim3(16, 64), blk, 0, stream>>>(Qr, Kr, Vt, Oa);
  gemm_bt<float><<<dim3(16, 32), blk, 0, stream>>>(Oa, wob, out, 4096, 2048, 2048);
}

// Round 3
// 393.118 us; speedup vs baseline: 1.6008x; 1.6008x over previous
//
#include <hip/hip_runtime.h>
#include <hip/hip_bf16.h>
#include <type_traits>

typedef __bf16 bf16;
typedef __bf16 bf16x2 __attribute__((ext_vector_type(2)));
typedef __bf16 bf16x4 __attribute__((ext_vector_type(4)));
typedef __bf16 bf16x8 __attribute__((ext_vector_type(8)));
typedef float f32x4 __attribute__((ext_vector_type(4)));

#define AS1 __attribute__((address_space(1)))
#define AS3 __attribute__((address_space(3)))

// Async global->LDS, 16B per lane. LDS dest is wave-uniform base + lane*16.
__device__ __forceinline__ void load_lds16(const void* g, void* l) {
  __builtin_amdgcn_global_load_lds((AS1 void*)g, (AS3 void*)l, 16, 0, 0);
}

// ---------------------------------------------------------------------------
// fp32 -> bf16 conversions
// ---------------------------------------------------------------------------
__global__ void f2b(const float* __restrict__ in, bf16* __restrict__ out, int n) {
  int i = (blockIdx.x * 256 + threadIdx.x) * 4;
  if (i < n) {
    float4 v = *(const float4*)(in + i);
    bf16x4 o = {(bf16)v.x, (bf16)v.y, (bf16)v.z, (bf16)v.w};
    *(bf16x4*)(out + i) = o;
  }
}

// all four weight matrices in one launch (wq 4M, wk 1M, wv 1M, wo 4M elems)
__global__ void f2b4(const float* __restrict__ a, const float* __restrict__ b,
                     const float* __restrict__ c, const float* __restrict__ d,
                     bf16* __restrict__ oa, bf16* __restrict__ ob,
                     bf16* __restrict__ oc, bf16* __restrict__ od) {
  int bid = blockIdx.x;
  const float* src;
  bf16* dst;
  int off;
  if (bid < 4096) { src = a; dst = oa; off = bid; }
  else if (bid < 5120) { src = b; dst = ob; off = bid - 4096; }
  else if (bid < 6144) { src = c; dst = oc; off = bid - 5120; }
  else { src = d; dst = od; off = bid - 6144; }
  int i = (off * 256 + threadIdx.x) * 4;
  float4 v = *(const float4*)(src + i);
  bf16x4 o = {(bf16)v.x, (bf16)v.y, (bf16)v.z, (bf16)v.w};
  *(bf16x4*)(dst + i) = o;
}

// ---------------------------------------------------------------------------
// GEMM: C[M][N] = A[M][K] * Bw[N][K]^T   (bf16 in, fp32 accumulate)
// ---------------------------------------------------------------------------
template <typename OutT>
__global__ __launch_bounds__(256) void gemm_bt(const bf16* __restrict__ A,
                                               const bf16* __restrict__ Bw,
                                               OutT* __restrict__ C,
                                               int M, int N, int K) {
  __shared__ bf16 As[128][32];
  __shared__ bf16 Bs[128][32];
  const int t = threadIdx.x;
  const int wave = t >> 6;
  const int lane = t & 63;
  const int qd = lane >> 4;
  const int ln = lane & 15;
  const int wm = (wave >> 1) * 64;
  const int wn = (wave & 1) * 64;
  const size_t bm = (size_t)blockIdx.y * 128;
  const size_t bn = (size_t)blockIdx.x * 128;

  const bf16* Ab = A + bm * (size_t)K;
  const bf16* Bb = Bw + bn * (size_t)K;

  f32x4 acc[4][4] = {};

  for (int k0 = 0; k0 < K; k0 += 32) {
#pragma unroll
    for (int i = 0; i < 2; i++) {
      int e = i * 256 + t;
      load_lds16(Ab + (size_t)(e >> 2) * K + k0 + (e & 3) * 8,
                 (char*)As + i * 4096 + wave * 1024);
      load_lds16(Bb + (size_t)(e >> 2) * K + k0 + (e & 3) * 8,
                 (char*)Bs + i * 4096 + wave * 1024);
    }
    __syncthreads();

    bf16x8 af[4], bfr[4];
#pragma unroll
    for (int i = 0; i < 4; i++)
      af[i] = *(const bf16x8*)&As[wm + i * 16 + ln][qd * 8];
#pragma unroll
    for (int j = 0; j < 4; j++)
      bfr[j] = *(const bf16x8*)&Bs[wn + j * 16 + ln][qd * 8];
#pragma unroll
    for (int i = 0; i < 4; i++)
#pragma unroll
      for (int j = 0; j < 4; j++)
        acc[i][j] = __builtin_amdgcn_mfma_f32_16x16x32_bf16(af[i], bfr[j],
                                                            acc[i][j], 0, 0, 0);
    __syncthreads();
  }

#pragma unroll
  for (int i = 0; i < 4; i++)
#pragma unroll
    for (int j = 0; j < 4; j++)
#pragma unroll
      for (int r = 0; r < 4; r++) {
        size_t row = bm + wm + i * 16 + qd * 4 + r;
        size_t col = bn + wn + j * 16 + ln;
        C[row * N + col] = (OutT)acc[i][j][r];
      }
}

// ---------------------------------------------------------------------------
// RoPE + permute, Q and K in one launch.
// Q: (B,S,32,64)->(B,32,S,64)   K: (B,S,8,64)->(B,8,S,64)
// ---------------------------------------------------------------------------
__global__ void rope_qk(const bf16* __restrict__ Qp, const bf16* __restrict__ Kp,
                        const float* __restrict__ fc, const float* __restrict__ fs,
                        bf16* __restrict__ Qr, bf16* __restrict__ Kr) {
  int bid = blockIdx.x;
  if (bid < 16384) {
    int idx = bid * 256 + threadIdx.x;
    int i = idx & 31, h = (idx >> 5) & 31, s = (idx >> 10) & 2047, b = idx >> 21;
    size_t src = ((size_t)(b * 2048 + s) * 32 + h) * 64 + 2 * i;
    bf16x2 v = *(const bf16x2*)(Qp + src);
    float tr = (float)v[0], ti = (float)v[1];
    float c = fc[s * 32 + i], sn = fs[s * 32 + i];
    size_t dst = ((size_t)(b * 32 + h) * 2048 + s) * 64 + 2 * i;
    bf16x2 o = {(bf16)(tr * c - ti * sn), (bf16)(tr * sn + ti * c)};
    *(bf16x2*)(Qr + dst) = o;
  } else {
    int idx = (bid - 16384) * 256 + threadIdx.x;
    int i = idx & 31, h = (idx >> 5) & 7, s = (idx >> 8) & 2047, b = idx >> 19;
    size_t src = ((size_t)(b * 2048 + s) * 8 + h) * 64 + 2 * i;
    bf16x2 v = *(const bf16x2*)(Kp + src);
    float tr = (float)v[0], ti = (float)v[1];
    float c = fc[s * 32 + i], sn = fs[s * 32 + i];
    size_t dst = ((size_t)(b * 8 + h) * 2048 + s) * 64 + 2 * i;
    bf16x2 o = {(bf16)(tr * c - ti * sn), (bf16)(tr * sn + ti * c)};
    *(bf16x2*)(Kr + dst) = o;
  }
}

// V transpose: (B,S,8,64) -> (B,8,64,S)
__global__ void vtrans(const bf16* __restrict__ Vp, bf16* __restrict__ Vt) {
  __shared__ bf16 tile[64][65];
  int b = blockIdx.y >> 3, kh = blockIdx.y & 7;
  int s0 = blockIdx.x * 64;
#pragma unroll
  for (int i = 0; i < 16; i++) {
    int e = i * 256 + threadIdx.x;
    int r = e >> 6, c = e & 63;
    tile[r][c] = Vp[((size_t)(b * 2048 + s0 + r) * 8 + kh) * 64 + c];
  }
  __syncthreads();
#pragma unroll
  for (int i = 0; i < 16; i++) {
    int e = i * 256 + threadIdx.x;
    int d = e >> 6, s = e & 63;
    Vt[((size_t)(b * 8 + kh) * 64 + d) * 2048 + s0 + s] = tile[s][d];
  }
}

// ---------------------------------------------------------------------------
// Flash attention v2 (S^T formulation), causal.
// Q:(B,32,S,64)  K:(B,8,S,64)  Vt:(B,8,64,S)  ->  O:(B,S,32,64)
// One block = 128 q rows of one (b,h); wave w owns q rows [w*32, w*32+32).
// S^T = K*Q^T: per lane 16 in-lane k-values per q-col -> cheap softmax.
// O^T = V^T*P^T accumulates with col=q=ln matching softmax state layout.
// All LDS tiles XOR-swizzled (16B seg ^= row&7) -> ~2-way conflicts max.
// ---------------------------------------------------------------------------
__global__ __launch_bounds__(256, 3) void attn_fwd(const bf16* __restrict__ Q,
                                                   const bf16* __restrict__ Kg,
                                                   const bf16* __restrict__ Vg,
                                                   bf16* __restrict__ O) {
  __shared__ bf16 Qs[128][64];
  __shared__ bf16 Ks[64][64];
  __shared__ bf16 Vs[64][64];   // [d][k]
  __shared__ bf16 Ps[128][64];  // [q][k], swizzled
  const int t = threadIdx.x;
  const int wave = t >> 6, lane = t & 63, qd = lane >> 4, ln = lane & 15;
  const int bid = blockIdx.x;
  const int qt = 15 - (bid >> 6);  // longest blocks dispatch first
  const int bh = bid & 63;
  const int b = bh >> 5, h = bh & 31, kh = h >> 2;
  const bf16* Qb = Q + ((size_t)(b * 32 + h) * 2048 + qt * 128) * 64;
  const bf16* Kb = Kg + (size_t)(b * 8 + kh) * 2048 * 64;
  const bf16* Vb = Vg + (size_t)(b * 8 + kh) * 64 * 2048;
  char* PsB = (char*)Ps;

  // stage Q tile, xor-swizzled segment choice
#pragma unroll
  for (int i = 0; i < 4; i++) {
    int e = i * 256 + t;
    int row = e >> 3, sg = (e & 7) ^ (row & 7);
    load_lds16(Qb + (size_t)row * 64 + sg * 8, (char*)Qs + i * 4096 + wave * 1024);
  }

  f32x4 o_acc[4][2] = {};  // [dj][mi]: O^T rows d=dj*16+qd*4+r, cols q=mi*16+ln
  float m_st[2] = {-1e30f, -1e30f}, l_st[2] = {0.f, 0.f};
  const int q0 = qt * 128 + wave * 32;
  const int nkb = 2 * qt + 2;

  for (int kb = 0; kb < nkb; kb++) {
    __syncthreads();  // prev iteration's LDS reads done before restage
#pragma unroll
    for (int i = 0; i < 2; i++) {
      int e = i * 256 + t;
      int row = e >> 3, sg = (e & 7) ^ (row & 7);
      load_lds16(Kb + (size_t)(kb * 64 + row) * 64 + sg * 8,
                 (char*)Ks + i * 4096 + wave * 1024);
      load_lds16(Vb + (size_t)row * 2048 + kb * 64 + sg * 8,
                 (char*)Vs + i * 4096 + wave * 1024);
    }
    __syncthreads();  // staging visible (Q covered on first iter)

    // S^T = K*Q^T : s_acc[j][mi], row k = j*16+qd*4+r, col q = mi*16+ln
    f32x4 s_acc[4][2] = {};
#pragma unroll
    for (int kk = 0; kk < 2; kk++) {
      bf16x8 ak[4], bq[2];
#pragma unroll
      for (int j = 0; j < 4; j++) {
        int row = j * 16 + ln;
        int ph = (kk * 4 + qd) ^ (ln & 7);
        ak[j] = *(const bf16x8*)((const char*)Ks + row * 128 + ph * 16);
      }
#pragma unroll
      for (int mi = 0; mi < 2; mi++) {
        int row = wave * 32 + mi * 16 + ln;
        int ph = (kk * 4 + qd) ^ (ln & 7);
        bq[mi] = *(const bf16x8*)((const char*)Qs + row * 128 + ph * 16);
      }
#pragma unroll
      for (int j = 0; j < 4; j++)
#pragma unroll
        for (int mi = 0; mi < 2; mi++)
          s_acc[j][mi] = __builtin_amdgcn_mfma_f32_16x16x32_bf16(
              ak[j], bq[mi], s_acc[j][mi], 0, 0, 0);
    }

    // online softmax: in-lane over 16 k values, 2 shuffles across quads
    auto smax = [&](auto maskc) {
      constexpr bool MASK = decltype(maskc)::value;
#pragma unroll
      for (int mi = 0; mi < 2; mi++) {
        const int qv = q0 + mi * 16 + ln;
        float sv[16];
        float mx = -1e30f;
#pragma unroll
        for (int j = 0; j < 4; j++)
#pragma unroll
          for (int r = 0; r < 4; r++) {
            float s = s_acc[j][mi][r] * 0.125f;
            if (MASK) {
              int k_glob = kb * 64 + j * 16 + qd * 4 + r;
              if (k_glob > qv) s += -32768.0f;
            }
            sv[j * 4 + r] = s;
            mx = fmaxf(mx, s);
          }
        mx = fmaxf(mx, __shfl_xor(mx, 16));
        mx = fmaxf(mx, __shfl_xor(mx, 32));
        float mnew = fmaxf(m_st[mi], mx);
        float alpha = __expf(m_st[mi] - mnew);
        m_st[mi] = mnew;
        float rs = 0.f;
        const int prow = wave * 32 + mi * 16 + ln;
#pragma unroll
        for (int j = 0; j < 4; j++) {
          bf16x4 pk;
#pragma unroll
          for (int r = 0; r < 4; r++) {
            float pv = __expf(sv[j * 4 + r] - mnew);
            rs += pv;
            pk[r] = (bf16)pv;
          }
          // P[q][k]: 8B store, phys seg = (j*2 + qd/2) ^ (ln&7), half = qd&1
          int ps = (j * 2 + (qd >> 1)) ^ (ln & 7);
          *(bf16x4*)(PsB + prow * 128 + ps * 16 + (qd & 1) * 8) = pk;
        }
        rs += __shfl_xor(rs, 16);
        rs += __shfl_xor(rs, 32);
        l_st[mi] = l_st[mi] * alpha + rs;
#pragma unroll
        for (int dj = 0; dj < 4; dj++) o_acc[dj][mi] *= alpha;
      }
    };
    if (kb * 64 + 63 > q0) smax(std::true_type{});
    else smax(std::false_type{});

    // O^T += V^T * P^T  (Ps is wave-private: no barrier, lgkmcnt handles it)
#pragma unroll
    for (int kk = 0; kk < 2; kk++) {
      bf16x8 av[4], bp[2];
#pragma unroll
      for (int dj = 0; dj < 4; dj++) {
        int row = dj * 16 + ln;
        int ph = (kk * 4 + qd) ^ (ln & 7);
        av[dj] = *(const bf16x8*)((const char*)Vs + row * 128 + ph * 16);
      }
#pragma unroll
      for (int mi = 0; mi < 2; mi++) {
        int prow = wave * 32 + mi * 16 + ln;
        int ph = (kk * 4 + qd) ^ (ln & 7);
        bp[mi] = *(const bf16x8*)(PsB + prow * 128 + ph * 16);
      }
#pragma unroll
      for (int dj = 0; dj < 4; dj++)
#pragma unroll
        for (int mi = 0; mi < 2; mi++)
          o_acc[dj][mi] = __builtin_amdgcn_mfma_f32_16x16x32_bf16(
              av[dj], bp[mi], o_acc[dj][mi], 0, 0, 0);
    }
  }

  // epilogue: O[(b, s=q, h, d)] = O^T[d][q] / l[q]
#pragma unroll
  for (int mi = 0; mi < 2; mi++) {
    float inv = 1.f / l_st[mi];
    int q_idx = qt * 128 + wave * 32 + mi * 16 + ln;
#pragma unroll
    for (int dj = 0; dj < 4; dj++) {
      bf16x4 ov;
#pragma unroll
      for (int r = 0; r < 4; r++) ov[r] = (bf16)(o_acc[dj][mi][r] * inv);
      *(bf16x4*)&O[((size_t)(b * 2048 + q_idx) * 32 + h) * 64 + dj * 16 + qd * 4] = ov;
    }
  }
}

// ---------------------------------------------------------------------------
extern "C" void kernel_launch(void* const* d_in, const int* in_sizes, int n_in,
                              void* d_out, int out_size, void* d_ws,
                              size_t ws_size, hipStream_t stream) {
  const float* x = (const float*)d_in[0];
  const float* fc = (const float*)d_in[1];
  const float* fs = (const float*)d_in[2];
  const float* wq = (const float*)d_in[3];
  const float* wk = (const float*)d_in[4];
  const float* wv = (const float*)d_in[5];
  const float* wo = (const float*)d_in[6];
  float* out = (float*)d_out;

  char* ws = (char*)d_ws;
  const size_t MB = (size_t)1 << 20;
  bf16* xb  = (bf16*)(ws + 0 * MB);   // 16 MB (4096,2048)
  bf16* wqb = (bf16*)(ws + 16 * MB);  // 8 MB
  bf16* wkb = (bf16*)(ws + 24 * MB);  // 2 MB
  bf16* wvb = (bf16*)(ws + 26 * MB);  // 2 MB
  bf16* wob = (bf16*)(ws + 28 * MB);  // 8 MB
  bf16* Qp  = (bf16*)(ws + 36 * MB);  // 16 MB (B,S,32,64)
  bf16* Kp  = (bf16*)(ws + 52 * MB);  // 4 MB
  bf16* Vp  = (bf16*)(ws + 56 * MB);  // 4 MB
  bf16* Qr  = (bf16*)(ws + 60 * MB);  // 16 MB (B,32,S,64)
  bf16* Kr  = (bf16*)(ws + 76 * MB);  // 4 MB  (B,8,S,64)
  bf16* Vt  = (bf16*)(ws + 80 * MB);  // 4 MB  (B,8,64,S)
  bf16* Oa  = (bf16*)(ws + 36 * MB);  // 16 MB reuses Qp (dead after rope)

  dim3 blk(256);
  f2b<<<8192, blk, 0, stream>>>(x, xb, 8388608);
  f2b4<<<10240, blk, 0, stream>>>(wq, wk, wv, wo, wqb, wkb, wvb, wob);

  gemm_bt<bf16><<<dim3(16, 32), blk, 0, stream>>>(xb, wqb, Qp, 4096, 2048, 2048);
  gemm_bt<bf16><<<dim3(4, 32), blk, 0, stream>>>(xb, wkb, Kp, 4096, 512, 2048);
  gemm_bt<bf16><<<dim3(4, 32), blk, 0, stream>>>(xb, wvb, Vp, 4096, 512, 2048);
  rope_qk<<<20480, blk, 0, stream>>>(Qp, Kp, fc, fs, Qr, Kr);
  vtrans<<<dim3(32, 16), blk, 0, stream>>>(Vp, Vt);
  attn_fwd<<<1024, blk, 0, stream>>>(Qr, Kr, Vt, Oa);
  gemm_bt<float><<<dim3(16, 32), blk, 0, stream>>>(Oa, wob, out, 4096, 2048, 2048);
}

// Round 4
// 321.316 us; speedup vs baseline: 1.9585x; 1.2235x over previous
//
#include <hip/hip_runtime.h>
#include <hip/hip_bf16.h>
#include <type_traits>

typedef __bf16 bf16;
typedef __bf16 bf16x2 __attribute__((ext_vector_type(2)));
typedef __bf16 bf16x4 __attribute__((ext_vector_type(4)));
typedef __bf16 bf16x8 __attribute__((ext_vector_type(8)));
typedef float f32x4 __attribute__((ext_vector_type(4)));

#define AS1 __attribute__((address_space(1)))
#define AS3 __attribute__((address_space(3)))

// 0.125 (1/sqrt(64)) * log2(e): folded into Q so attn scores are log2-domain.
#define KAPPA 0.180336880111f

__device__ __forceinline__ void load_lds16(const void* g, void* l) {
  __builtin_amdgcn_global_load_lds((AS1 void*)g, (AS3 void*)l, 16, 0, 0);
}
__device__ __forceinline__ float exp2_fast(float x) {
  return __builtin_amdgcn_exp2f(x);
}

// ---------------------------------------------------------------------------
// All fp32->bf16 conversions in one launch.
// x: 8M elems -> xb.  wq(4M),wk(1M),wv(1M) -> wqkv rows [0,2048|2560|3072).
// wo: 4M -> wob.
// ---------------------------------------------------------------------------
__global__ void f2b_all(const float* __restrict__ x, const float* __restrict__ wq,
                        const float* __restrict__ wk, const float* __restrict__ wv,
                        const float* __restrict__ wo, bf16* __restrict__ xb,
                        bf16* __restrict__ wqkv, bf16* __restrict__ wob) {
  int bid = blockIdx.x;
  const float* src;
  bf16* dst;
  int off;
  if (bid < 8192) { src = x; dst = xb; off = bid; }
  else if (bid < 12288) { src = wq; dst = wqkv; off = bid - 8192; }
  else if (bid < 13312) { src = wk; dst = wqkv + 4194304; off = bid - 12288; }
  else if (bid < 14336) { src = wv; dst = wqkv + 5242880; off = bid - 13312; }
  else { src = wo; dst = wob; off = bid - 14336; }
  int i = (off * 256 + threadIdx.x) * 4;
  float4 v = *(const float4*)(src + i);
  bf16x4 o = {(bf16)v.x, (bf16)v.y, (bf16)v.z, (bf16)v.w};
  *(bf16x4*)(dst + i) = o;
}

// ---------------------------------------------------------------------------
// Fused QKV projection GEMM: [4096 x 2048] @ [3072 x 2048]^T.
// Epilogue by n-region:
//   bn<16 : Q + rope, scaled by KAPPA -> Qro (B,S,32,64)
//   bn<20 : K + rope                  -> Kro (B,S,8,64)
//   else  : V, transposed             -> Vt  (B,8,64,S)
// Rope pairs are adjacent columns = adjacent lanes -> shfl_xor(1).
// ---------------------------------------------------------------------------
__global__ __launch_bounds__(256) void gemm_qkv(const bf16* __restrict__ A,
                                                const bf16* __restrict__ Bw,
                                                const float* __restrict__ fc,
                                                const float* __restrict__ fs,
                                                bf16* __restrict__ Qro,
                                                bf16* __restrict__ Kro,
                                                bf16* __restrict__ Vt) {
  const int K = 2048;
  __shared__ bf16 As[128][32];
  __shared__ bf16 Bs[128][32];
  const int t = threadIdx.x;
  const int wave = t >> 6, lane = t & 63, qd = lane >> 4, ln = lane & 15;
  const int wm = (wave >> 1) * 64;
  const int wn = (wave & 1) * 64;
  const int bn = blockIdx.x;
  const size_t bm = (size_t)blockIdx.y * 128;

  const bf16* Ab = A + bm * (size_t)K;
  const bf16* Bb = Bw + (size_t)bn * 128 * K;

  f32x4 acc[4][4] = {};

  for (int k0 = 0; k0 < K; k0 += 32) {
#pragma unroll
    for (int i = 0; i < 2; i++) {
      int e = i * 256 + t;
      load_lds16(Ab + (size_t)(e >> 2) * K + k0 + (e & 3) * 8,
                 (char*)As + i * 4096 + wave * 1024);
      load_lds16(Bb + (size_t)(e >> 2) * K + k0 + (e & 3) * 8,
                 (char*)Bs + i * 4096 + wave * 1024);
    }
    __syncthreads();

    bf16x8 af[4], bfr[4];
#pragma unroll
    for (int i = 0; i < 4; i++)
      af[i] = *(const bf16x8*)&As[wm + i * 16 + ln][qd * 8];
#pragma unroll
    for (int j = 0; j < 4; j++)
      bfr[j] = *(const bf16x8*)&Bs[wn + j * 16 + ln][qd * 8];
#pragma unroll
    for (int i = 0; i < 4; i++)
#pragma unroll
      for (int j = 0; j < 4; j++)
        acc[i][j] = __builtin_amdgcn_mfma_f32_16x16x32_bf16(af[i], bfr[j],
                                                            acc[i][j], 0, 0, 0);
    __syncthreads();
  }

  // ---- epilogue ----
  const int b = (int)(bm >> 11);
  const int sb = (int)(bm & 2047) + wm;  // + i*16 + qd*4 + r = s
  const bool odd = ln & 1;

  if (bn < 20) {  // Q or K: rope
    const bool isQ = bn < 16;
    const float kap = isQ ? KAPPA : 1.0f;
    const int hh = isQ ? (bn * 2 + (wn >> 6)) : ((bn - 16) * 2 + (wn >> 6));
#pragma unroll
    for (int i = 0; i < 4; i++) {
#pragma unroll
      for (int j = 0; j < 4; j++) {
        const int d = j * 16 + ln;
        const int i_f = d >> 1;
#pragma unroll
        for (int r = 0; r < 4; r++) {
          int s = sb + i * 16 + qd * 4 + r;
          float v = acc[i][j][r];
          float p = __shfl_xor(v, 1);
          float cv = fc[s * 32 + i_f] * kap;
          float sv = fs[s * 32 + i_f] * kap;
          float o = odd ? (p * sv + v * cv) : (v * cv - p * sv);
          if (isQ)
            Qro[((size_t)(b * 2048 + s) * 32 + hh) * 64 + d] = (bf16)o;
          else
            Kro[((size_t)(b * 2048 + s) * 8 + hh) * 64 + d] = (bf16)o;
        }
      }
    }
  } else {  // V: write transposed (B,8,64,S)
    const int kh = (bn - 20) * 2 + (wn >> 6);
#pragma unroll
    for (int i = 0; i < 4; i++)
#pragma unroll
      for (int j = 0; j < 4; j++) {
        const int d = j * 16 + ln;
        int s = sb + i * 16 + qd * 4;
        bf16x4 ov = {(bf16)acc[i][j][0], (bf16)acc[i][j][1],
                     (bf16)acc[i][j][2], (bf16)acc[i][j][3]};
        *(bf16x4*)&Vt[((size_t)(b * 8 + kh) * 64 + d) * 2048 + s] = ov;
      }
  }
}

// ---------------------------------------------------------------------------
// Plain GEMM for the output projection: C[M][N] = A[M][K] * Bw[N][K]^T.
// ---------------------------------------------------------------------------
template <typename OutT>
__global__ __launch_bounds__(256) void gemm_bt(const bf16* __restrict__ A,
                                               const bf16* __restrict__ Bw,
                                               OutT* __restrict__ C,
                                               int M, int N, int K) {
  __shared__ bf16 As[128][32];
  __shared__ bf16 Bs[128][32];
  const int t = threadIdx.x;
  const int wave = t >> 6, lane = t & 63, qd = lane >> 4, ln = lane & 15;
  const int wm = (wave >> 1) * 64;
  const int wn = (wave & 1) * 64;
  const size_t bm = (size_t)blockIdx.y * 128;
  const size_t bn = (size_t)blockIdx.x * 128;

  const bf16* Ab = A + bm * (size_t)K;
  const bf16* Bb = Bw + bn * (size_t)K;

  f32x4 acc[4][4] = {};

  for (int k0 = 0; k0 < K; k0 += 32) {
#pragma unroll
    for (int i = 0; i < 2; i++) {
      int e = i * 256 + t;
      load_lds16(Ab + (size_t)(e >> 2) * K + k0 + (e & 3) * 8,
                 (char*)As + i * 4096 + wave * 1024);
      load_lds16(Bb + (size_t)(e >> 2) * K + k0 + (e & 3) * 8,
                 (char*)Bs + i * 4096 + wave * 1024);
    }
    __syncthreads();

    bf16x8 af[4], bfr[4];
#pragma unroll
    for (int i = 0; i < 4; i++)
      af[i] = *(const bf16x8*)&As[wm + i * 16 + ln][qd * 8];
#pragma unroll
    for (int j = 0; j < 4; j++)
      bfr[j] = *(const bf16x8*)&Bs[wn + j * 16 + ln][qd * 8];
#pragma unroll
    for (int i = 0; i < 4; i++)
#pragma unroll
      for (int j = 0; j < 4; j++)
        acc[i][j] = __builtin_amdgcn_mfma_f32_16x16x32_bf16(af[i], bfr[j],
                                                            acc[i][j], 0, 0, 0);
    __syncthreads();
  }

#pragma unroll
  for (int i = 0; i < 4; i++)
#pragma unroll
    for (int j = 0; j < 4; j++)
#pragma unroll
      for (int r = 0; r < 4; r++) {
        size_t row = bm + wm + i * 16 + qd * 4 + r;
        size_t col = bn + wn + j * 16 + ln;
        C[row * N + col] = (OutT)acc[i][j][r];
      }
}

// ---------------------------------------------------------------------------
// Flash attention (S^T formulation), causal. Scores arrive pre-scaled to the
// log2 domain (Q folded KAPPA), so softmax uses raw v_exp_f32.
// Q:(B,S,32,64)  K:(B,S,8,64)  Vt:(B,8,64,S)  ->  O:(B,S,32,64)
// ---------------------------------------------------------------------------
__global__ __launch_bounds__(256, 3) void attn_fwd(const bf16* __restrict__ Q,
                                                   const bf16* __restrict__ Kg,
                                                   const bf16* __restrict__ Vg,
                                                   bf16* __restrict__ O) {
  __shared__ bf16 Qs[128][64];
  __shared__ bf16 Ks[64][64];
  __shared__ bf16 Vs[64][64];   // [d][k]
  __shared__ bf16 Ps[128][64];  // [q][k], swizzled
  const int t = threadIdx.x;
  const int wave = t >> 6, lane = t & 63, qd = lane >> 4, ln = lane & 15;
  const int bid = blockIdx.x;
  const int qt = 15 - (bid >> 6);  // longest blocks dispatch first
  const int bh = bid & 63;
  const int b = bh >> 5, h = bh & 31, kh = h >> 2;
  // strided row reads straight from the GEMM-native layouts
  const bf16* Qb = Q + ((size_t)(b * 2048 + qt * 128) * 32 + h) * 64;  // row stride 2048
  const bf16* Kb = Kg + ((size_t)(b * 2048) * 8 + kh) * 64;            // row stride 512
  const bf16* Vb = Vg + (size_t)(b * 8 + kh) * 64 * 2048;              // row stride 2048
  char* PsB = (char*)Ps;

#pragma unroll
  for (int i = 0; i < 4; i++) {
    int e = i * 256 + t;
    int row = e >> 3, sg = (e & 7) ^ (row & 7);
    load_lds16(Qb + (size_t)row * 2048 + sg * 8, (char*)Qs + i * 4096 + wave * 1024);
  }

  f32x4 o_acc[4][2] = {};
  float m_st[2] = {-1e30f, -1e30f}, l_st[2] = {0.f, 0.f};
  const int q0 = qt * 128 + wave * 32;
  const int nkb = 2 * qt + 2;

  for (int kb = 0; kb < nkb; kb++) {
    __syncthreads();
#pragma unroll
    for (int i = 0; i < 2; i++) {
      int e = i * 256 + t;
      int row = e >> 3, sg = (e & 7) ^ (row & 7);
      load_lds16(Kb + (size_t)(kb * 64 + row) * 512 + sg * 8,
                 (char*)Ks + i * 4096 + wave * 1024);
      load_lds16(Vb + (size_t)row * 2048 + kb * 64 + sg * 8,
                 (char*)Vs + i * 4096 + wave * 1024);
    }
    __syncthreads();

    // S^T = K*Q^T
    f32x4 s_acc[4][2] = {};
#pragma unroll
    for (int kk = 0; kk < 2; kk++) {
      bf16x8 ak[4], bq[2];
#pragma unroll
      for (int j = 0; j < 4; j++) {
        int row = j * 16 + ln;
        int ph = (kk * 4 + qd) ^ (ln & 7);
        ak[j] = *(const bf16x8*)((const char*)Ks + row * 128 + ph * 16);
      }
#pragma unroll
      for (int mi = 0; mi < 2; mi++) {
        int row = wave * 32 + mi * 16 + ln;
        int ph = (kk * 4 + qd) ^ (ln & 7);
        bq[mi] = *(const bf16x8*)((const char*)Qs + row * 128 + ph * 16);
      }
#pragma unroll
      for (int j = 0; j < 4; j++)
#pragma unroll
        for (int mi = 0; mi < 2; mi++)
          s_acc[j][mi] = __builtin_amdgcn_mfma_f32_16x16x32_bf16(
              ak[j], bq[mi], s_acc[j][mi], 0, 0, 0);
    }

    // online softmax, log2 domain
    auto smax = [&](auto maskc) {
      constexpr bool MASK = decltype(maskc)::value;
#pragma unroll
      for (int mi = 0; mi < 2; mi++) {
        const int qv = q0 + mi * 16 + ln;
        float sv[16];
        float mx = -1e30f;
#pragma unroll
        for (int j = 0; j < 4; j++)
#pragma unroll
          for (int r = 0; r < 4; r++) {
            float s = s_acc[j][mi][r];
            if (MASK) {
              int k_glob = kb * 64 + j * 16 + qd * 4 + r;
              if (k_glob > qv) s = -1e5f;
            }
            sv[j * 4 + r] = s;
            mx = fmaxf(mx, s);
          }
        mx = fmaxf(mx, __shfl_xor(mx, 16));
        mx = fmaxf(mx, __shfl_xor(mx, 32));
        float mnew = fmaxf(m_st[mi], mx);
        float alpha = exp2_fast(m_st[mi] - mnew);
        m_st[mi] = mnew;
        float rs = 0.f;
        const int prow = wave * 32 + mi * 16 + ln;
#pragma unroll
        for (int j = 0; j < 4; j++) {
          bf16x4 pk;
#pragma unroll
          for (int r = 0; r < 4; r++) {
            float pv = exp2_fast(sv[j * 4 + r] - mnew);
            rs += pv;
            pk[r] = (bf16)pv;
          }
          int ps = (j * 2 + (qd >> 1)) ^ (ln & 7);
          *(bf16x4*)(PsB + prow * 128 + ps * 16 + (qd & 1) * 8) = pk;
        }
        rs += __shfl_xor(rs, 16);
        rs += __shfl_xor(rs, 32);
        l_st[mi] = l_st[mi] * alpha + rs;
#pragma unroll
        for (int dj = 0; dj < 4; dj++) o_acc[dj][mi] *= alpha;
      }
    };
    if (kb * 64 + 63 > q0) smax(std::true_type{});
    else smax(std::false_type{});

    // O^T += V^T * P^T  (Ps wave-private; lgkmcnt orders write->read)
#pragma unroll
    for (int kk = 0; kk < 2; kk++) {
      bf16x8 av[4], bp[2];
#pragma unroll
      for (int dj = 0; dj < 4; dj++) {
        int row = dj * 16 + ln;
        int ph = (kk * 4 + qd) ^ (ln & 7);
        av[dj] = *(const bf16x8*)((const char*)Vs + row * 128 + ph * 16);
      }
#pragma unroll
      for (int mi = 0; mi < 2; mi++) {
        int prow = wave * 32 + mi * 16 + ln;
        int ph = (kk * 4 + qd) ^ (ln & 7);
        bp[mi] = *(const bf16x8*)(PsB + prow * 128 + ph * 16);
      }
#pragma unroll
      for (int dj = 0; dj < 4; dj++)
#pragma unroll
        for (int mi = 0; mi < 2; mi++)
          o_acc[dj][mi] = __builtin_amdgcn_mfma_f32_16x16x32_bf16(
              av[dj], bp[mi], o_acc[dj][mi], 0, 0, 0);
    }
  }

#pragma unroll
  for (int mi = 0; mi < 2; mi++) {
    float inv = 1.f / l_st[mi];
    int q_idx = qt * 128 + wave * 32 + mi * 16 + ln;
#pragma unroll
    for (int dj = 0; dj < 4; dj++) {
      bf16x4 ov;
#pragma unroll
      for (int r = 0; r < 4; r++) ov[r] = (bf16)(o_acc[dj][mi][r] * inv);
      *(bf16x4*)&O[((size_t)(b * 2048 + q_idx) * 32 + h) * 64 + dj * 16 + qd * 4] = ov;
    }
  }
}

// ---------------------------------------------------------------------------
extern "C" void kernel_launch(void* const* d_in, const int* in_sizes, int n_in,
                              void* d_out, int out_size, void* d_ws,
                              size_t ws_size, hipStream_t stream) {
  const float* x = (const float*)d_in[0];
  const float* fc = (const float*)d_in[1];
  const float* fs = (const float*)d_in[2];
  const float* wq = (const float*)d_in[3];
  const float* wk = (const float*)d_in[4];
  const float* wv = (const float*)d_in[5];
  const float* wo = (const float*)d_in[6];
  float* out = (float*)d_out;

  char* ws = (char*)d_ws;
  const size_t MB = (size_t)1 << 20;
  bf16* xb   = (bf16*)(ws + 0 * MB);   // 16 MB (4096,2048)
  bf16* wqkv = (bf16*)(ws + 16 * MB);  // 12 MB (3072,2048)
  bf16* wob  = (bf16*)(ws + 28 * MB);  // 8 MB
  bf16* Qro  = (bf16*)(ws + 36 * MB);  // 16 MB (B,S,32,64), roped*KAPPA
  bf16* Kro  = (bf16*)(ws + 52 * MB);  // 4 MB  (B,S,8,64), roped
  bf16* Vt   = (bf16*)(ws + 56 * MB);  // 4 MB  (B,8,64,S)
  bf16* Oa   = (bf16*)(ws + 60 * MB);  // 16 MB (B,S,32,64)

  dim3 blk(256);
  f2b_all<<<18432, blk, 0, stream>>>(x, wq, wk, wv, wo, xb, wqkv, wob);
  gemm_qkv<<<dim3(24, 32), blk, 0, stream>>>(xb, wqkv, fc, fs, Qro, Kro, Vt);
  attn_fwd<<<1024, blk, 0, stream>>>(Qro, Kro, Vt, Oa);
  gemm_bt<float><<<dim3(16, 32), blk, 0, stream>>>(Oa, wob, out, 4096, 2048, 2048);
}

// Round 5
// 318.360 us; speedup vs baseline: 1.9766x; 1.0093x over previous
//
#include <hip/hip_runtime.h>
#include <hip/hip_bf16.h>
#include <type_traits>

typedef __bf16 bf16;
typedef __bf16 bf16x2 __attribute__((ext_vector_type(2)));
typedef __bf16 bf16x4 __attribute__((ext_vector_type(4)));
typedef __bf16 bf16x8 __attribute__((ext_vector_type(8)));
typedef float f32x4 __attribute__((ext_vector_type(4)));

#define AS1 __attribute__((address_space(1)))
#define AS3 __attribute__((address_space(3)))

// 0.125 (1/sqrt(64)) * log2(e): folded into Q so attn scores are log2-domain.
#define KAPPA 0.180336880111f

__device__ __forceinline__ void load_lds16(const void* g, void* l) {
  __builtin_amdgcn_global_load_lds((AS1 void*)g, (AS3 void*)l, 16, 0, 0);
}
__device__ __forceinline__ float exp2_fast(float x) {
  return __builtin_amdgcn_exp2f(x);
}

// ---------------------------------------------------------------------------
// All fp32->bf16 conversions in one launch.
// ---------------------------------------------------------------------------
__global__ void f2b_all(const float* __restrict__ x, const float* __restrict__ wq,
                        const float* __restrict__ wk, const float* __restrict__ wv,
                        const float* __restrict__ wo, bf16* __restrict__ xb,
                        bf16* __restrict__ wqkv, bf16* __restrict__ wob) {
  int bid = blockIdx.x;
  const float* src;
  bf16* dst;
  int off;
  if (bid < 8192) { src = x; dst = xb; off = bid; }
  else if (bid < 12288) { src = wq; dst = wqkv; off = bid - 8192; }
  else if (bid < 13312) { src = wk; dst = wqkv + 4194304; off = bid - 12288; }
  else if (bid < 14336) { src = wv; dst = wqkv + 5242880; off = bid - 13312; }
  else { src = wo; dst = wob; off = bid - 14336; }
  int i = (off * 256 + threadIdx.x) * 4;
  float4 v = *(const float4*)(src + i);
  bf16x4 o = {(bf16)v.x, (bf16)v.y, (bf16)v.z, (bf16)v.w};
  *(bf16x4*)(dst + i) = o;
}

// ---------------------------------------------------------------------------
// Fused QKV projection GEMM: [4096 x 2048] @ [3072 x 2048]^T, 128x128 tile.
// LDS tiles XOR-swizzled: physical seg ps holds global seg ps^(row&3).
// Epilogue: bn<16 Q+rope*KAPPA -> Qro; bn<20 K+rope -> Kro; else V^T -> Vt.
// ---------------------------------------------------------------------------
__global__ __launch_bounds__(256) void gemm_qkv(const bf16* __restrict__ A,
                                                const bf16* __restrict__ Bw,
                                                const float* __restrict__ fc,
                                                const float* __restrict__ fs,
                                                bf16* __restrict__ Qro,
                                                bf16* __restrict__ Kro,
                                                bf16* __restrict__ Vt) {
  const int K = 2048;
  __shared__ bf16 As[128][32];
  __shared__ bf16 Bs[128][32];
  const int t = threadIdx.x;
  const int wave = t >> 6, lane = t & 63, qd = lane >> 4, ln = lane & 15;
  const int wm = (wave >> 1) * 64;
  const int wn = (wave & 1) * 64;
  const int bn = blockIdx.x;
  const size_t bm = (size_t)blockIdx.y * 128;

  const bf16* Ab = A + bm * (size_t)K;
  const bf16* Bb = Bw + (size_t)bn * 128 * K;

  f32x4 acc[4][4] = {};

  for (int k0 = 0; k0 < K; k0 += 32) {
#pragma unroll
    for (int i = 0; i < 2; i++) {
      int e = i * 256 + t;
      int ro = e >> 2, gs = (e & 3) ^ (ro & 3);
      load_lds16(Ab + (size_t)ro * K + k0 + gs * 8,
                 (char*)As + i * 4096 + wave * 1024);
      load_lds16(Bb + (size_t)ro * K + k0 + gs * 8,
                 (char*)Bs + i * 4096 + wave * 1024);
    }
    __syncthreads();

    bf16x8 af[4], bfr[4];
#pragma unroll
    for (int i = 0; i < 4; i++) {
      int row = wm + i * 16 + ln;
      af[i] = *(const bf16x8*)((const char*)As + row * 64 + (qd ^ (row & 3)) * 16);
    }
#pragma unroll
    for (int j = 0; j < 4; j++) {
      int row = wn + j * 16 + ln;
      bfr[j] = *(const bf16x8*)((const char*)Bs + row * 64 + (qd ^ (row & 3)) * 16);
    }
#pragma unroll
    for (int i = 0; i < 4; i++)
#pragma unroll
      for (int j = 0; j < 4; j++)
        acc[i][j] = __builtin_amdgcn_mfma_f32_16x16x32_bf16(af[i], bfr[j],
                                                            acc[i][j], 0, 0, 0);
    __syncthreads();
  }

  // ---- epilogue ----
  const int b = (int)(bm >> 11);
  const int sb = (int)(bm & 2047) + wm;
  const bool odd = ln & 1;

  if (bn < 20) {  // Q or K: rope
    const bool isQ = bn < 16;
    const float kap = isQ ? KAPPA : 1.0f;
    const int hh = isQ ? (bn * 2 + (wn >> 6)) : ((bn - 16) * 2 + (wn >> 6));
#pragma unroll
    for (int i = 0; i < 4; i++) {
#pragma unroll
      for (int j = 0; j < 4; j++) {
        const int d = j * 16 + ln;
        const int i_f = d >> 1;
#pragma unroll
        for (int r = 0; r < 4; r++) {
          int s = sb + i * 16 + qd * 4 + r;
          float v = acc[i][j][r];
          float p = __shfl_xor(v, 1);
          float cv = fc[s * 32 + i_f] * kap;
          float sv = fs[s * 32 + i_f] * kap;
          float o = odd ? (p * sv + v * cv) : (v * cv - p * sv);
          if (isQ)
            Qro[((size_t)(b * 2048 + s) * 32 + hh) * 64 + d] = (bf16)o;
          else
            Kro[((size_t)(b * 2048 + s) * 8 + hh) * 64 + d] = (bf16)o;
        }
      }
    }
  } else {  // V: write transposed (B,8,64,S)
    const int kh = (bn - 20) * 2 + (wn >> 6);
#pragma unroll
    for (int i = 0; i < 4; i++)
#pragma unroll
      for (int j = 0; j < 4; j++) {
        const int d = j * 16 + ln;
        int s = sb + i * 16 + qd * 4;
        bf16x4 ov = {(bf16)acc[i][j][0], (bf16)acc[i][j][1],
                     (bf16)acc[i][j][2], (bf16)acc[i][j][3]};
        *(bf16x4*)&Vt[((size_t)(b * 8 + kh) * 64 + d) * 2048 + s] = ov;
      }
  }
}

// ---------------------------------------------------------------------------
// Output projection GEMM, 64x128 tile (grid 1024 = 4 blocks/CU).
// Wave-tile 32x64 (2x2 waves). Swizzled LDS. C[M][N] = A[M][K]*Bw[N][K]^T.
// ---------------------------------------------------------------------------
template <typename OutT>
__global__ __launch_bounds__(256, 4) void gemm_bt64(const bf16* __restrict__ A,
                                                    const bf16* __restrict__ Bw,
                                                    OutT* __restrict__ C,
                                                    int M, int N, int K) {
  __shared__ bf16 As[64][32];
  __shared__ bf16 Bs[128][32];
  const int t = threadIdx.x;
  const int wave = t >> 6, lane = t & 63, qd = lane >> 4, ln = lane & 15;
  const int wm = (wave >> 1) * 32;
  const int wn = (wave & 1) * 64;
  const size_t bm = (size_t)blockIdx.y * 64;
  const size_t bn = (size_t)blockIdx.x * 128;

  const bf16* Ab = A + bm * (size_t)K;
  const bf16* Bb = Bw + bn * (size_t)K;

  f32x4 acc[2][4] = {};

  for (int k0 = 0; k0 < K; k0 += 32) {
    {
      int e = t;  // As: 64 rows x 4 segs = 256 slots, one round
      int ro = e >> 2, gs = (e & 3) ^ (ro & 3);
      load_lds16(Ab + (size_t)ro * K + k0 + gs * 8, (char*)As + wave * 1024);
    }
#pragma unroll
    for (int i = 0; i < 2; i++) {
      int e = i * 256 + t;
      int ro = e >> 2, gs = (e & 3) ^ (ro & 3);
      load_lds16(Bb + (size_t)ro * K + k0 + gs * 8,
                 (char*)Bs + i * 4096 + wave * 1024);
    }
    __syncthreads();

    bf16x8 af[2], bfr[4];
#pragma unroll
    for (int i = 0; i < 2; i++) {
      int row = wm + i * 16 + ln;
      af[i] = *(const bf16x8*)((const char*)As + row * 64 + (qd ^ (row & 3)) * 16);
    }
#pragma unroll
    for (int j = 0; j < 4; j++) {
      int row = wn + j * 16 + ln;
      bfr[j] = *(const bf16x8*)((const char*)Bs + row * 64 + (qd ^ (row & 3)) * 16);
    }
#pragma unroll
    for (int i = 0; i < 2; i++)
#pragma unroll
      for (int j = 0; j < 4; j++)
        acc[i][j] = __builtin_amdgcn_mfma_f32_16x16x32_bf16(af[i], bfr[j],
                                                            acc[i][j], 0, 0, 0);
    __syncthreads();
  }

#pragma unroll
  for (int i = 0; i < 2; i++)
#pragma unroll
    for (int j = 0; j < 4; j++)
#pragma unroll
      for (int r = 0; r < 4; r++) {
        size_t row = bm + wm + i * 16 + qd * 4 + r;
        size_t col = bn + wn + j * 16 + ln;
        C[row * N + col] = (OutT)acc[i][j][r];
      }
}

// ---------------------------------------------------------------------------
// Flash attention (S^T formulation), causal, log2-domain softmax.
// Q:(B,S,32,64)  K:(B,S,8,64)  Vt:(B,8,64,S)  ->  O:(B,S,32,64)
// ---------------------------------------------------------------------------
__global__ __launch_bounds__(256, 3) void attn_fwd(const bf16* __restrict__ Q,
                                                   const bf16* __restrict__ Kg,
                                                   const bf16* __restrict__ Vg,
                                                   bf16* __restrict__ O) {
  __shared__ bf16 Qs[128][64];
  __shared__ bf16 Ks[64][64];
  __shared__ bf16 Vs[64][64];   // [d][k]
  __shared__ bf16 Ps[128][64];  // [q][k], swizzled
  const int t = threadIdx.x;
  const int wave = t >> 6, lane = t & 63, qd = lane >> 4, ln = lane & 15;
  const int bid = blockIdx.x;
  const int qt = 15 - (bid >> 6);  // longest blocks dispatch first
  const int bh = bid & 63;
  const int b = bh >> 5, h = bh & 31, kh = h >> 2;
  const bf16* Qb = Q + ((size_t)(b * 2048 + qt * 128) * 32 + h) * 64;  // row stride 2048
  const bf16* Kb = Kg + ((size_t)(b * 2048) * 8 + kh) * 64;            // row stride 512
  const bf16* Vb = Vg + (size_t)(b * 8 + kh) * 64 * 2048;              // row stride 2048
  char* PsB = (char*)Ps;

#pragma unroll
  for (int i = 0; i < 4; i++) {
    int e = i * 256 + t;
    int row = e >> 3, sg = (e & 7) ^ (row & 7);
    load_lds16(Qb + (size_t)row * 2048 + sg * 8, (char*)Qs + i * 4096 + wave * 1024);
  }

  f32x4 o_acc[4][2] = {};
  float m_st[2] = {-1e30f, -1e30f}, l_st[2] = {0.f, 0.f};
  const int q0 = qt * 128 + wave * 32;
  const int nkb = 2 * qt + 2;

  for (int kb = 0; kb < nkb; kb++) {
    __syncthreads();
#pragma unroll
    for (int i = 0; i < 2; i++) {
      int e = i * 256 + t;
      int row = e >> 3, sg = (e & 7) ^ (row & 7);
      load_lds16(Kb + (size_t)(kb * 64 + row) * 512 + sg * 8,
                 (char*)Ks + i * 4096 + wave * 1024);
      load_lds16(Vb + (size_t)row * 2048 + kb * 64 + sg * 8,
                 (char*)Vs + i * 4096 + wave * 1024);
    }
    __syncthreads();

    // S^T = K*Q^T
    f32x4 s_acc[4][2] = {};
#pragma unroll
    for (int kk = 0; kk < 2; kk++) {
      bf16x8 ak[4], bq[2];
#pragma unroll
      for (int j = 0; j < 4; j++) {
        int row = j * 16 + ln;
        int ph = (kk * 4 + qd) ^ (ln & 7);
        ak[j] = *(const bf16x8*)((const char*)Ks + row * 128 + ph * 16);
      }
#pragma unroll
      for (int mi = 0; mi < 2; mi++) {
        int row = wave * 32 + mi * 16 + ln;
        int ph = (kk * 4 + qd) ^ (ln & 7);
        bq[mi] = *(const bf16x8*)((const char*)Qs + row * 128 + ph * 16);
      }
#pragma unroll
      for (int j = 0; j < 4; j++)
#pragma unroll
        for (int mi = 0; mi < 2; mi++)
          s_acc[j][mi] = __builtin_amdgcn_mfma_f32_16x16x32_bf16(
              ak[j], bq[mi], s_acc[j][mi], 0, 0, 0);
    }

    // online softmax, log2 domain
    auto smax = [&](auto maskc) {
      constexpr bool MASK = decltype(maskc)::value;
#pragma unroll
      for (int mi = 0; mi < 2; mi++) {
        const int qv = q0 + mi * 16 + ln;
        float sv[16];
        float mx = -1e30f;
#pragma unroll
        for (int j = 0; j < 4; j++)
#pragma unroll
          for (int r = 0; r < 4; r++) {
            float s = s_acc[j][mi][r];
            if (MASK) {
              int k_glob = kb * 64 + j * 16 + qd * 4 + r;
              if (k_glob > qv) s = -1e5f;
            }
            sv[j * 4 + r] = s;
            mx = fmaxf(mx, s);
          }
        mx = fmaxf(mx, __shfl_xor(mx, 16));
        mx = fmaxf(mx, __shfl_xor(mx, 32));
        float mnew = fmaxf(m_st[mi], mx);
        float alpha = exp2_fast(m_st[mi] - mnew);
        m_st[mi] = mnew;
        float rs = 0.f;
        const int prow = wave * 32 + mi * 16 + ln;
#pragma unroll
        for (int j = 0; j < 4; j++) {
          bf16x4 pk;
#pragma unroll
          for (int r = 0; r < 4; r++) {
            float pv = exp2_fast(sv[j * 4 + r] - mnew);
            rs += pv;
            pk[r] = (bf16)pv;
          }
          int ps = (j * 2 + (qd >> 1)) ^ (ln & 7);
          *(bf16x4*)(PsB + prow * 128 + ps * 16 + (qd & 1) * 8) = pk;
        }
        rs += __shfl_xor(rs, 16);
        rs += __shfl_xor(rs, 32);
        l_st[mi] = l_st[mi] * alpha + rs;
#pragma unroll
        for (int dj = 0; dj < 4; dj++) o_acc[dj][mi] *= alpha;
      }
    };
    if (kb * 64 + 63 > q0) smax(std::true_type{});
    else smax(std::false_type{});

    // O^T += V^T * P^T  (Ps wave-private; lgkmcnt orders write->read)
#pragma unroll
    for (int kk = 0; kk < 2; kk++) {
      bf16x8 av[4], bp[2];
#pragma unroll
      for (int dj = 0; dj < 4; dj++) {
        int row = dj * 16 + ln;
        int ph = (kk * 4 + qd) ^ (ln & 7);
        av[dj] = *(const bf16x8*)((const char*)Vs + row * 128 + ph * 16);
      }
#pragma unroll
      for (int mi = 0; mi < 2; mi++) {
        int prow = wave * 32 + mi * 16 + ln;
        int ph = (kk * 4 + qd) ^ (ln & 7);
        bp[mi] = *(const bf16x8*)(PsB + prow * 128 + ph * 16);
      }
#pragma unroll
      for (int dj = 0; dj < 4; dj++)
#pragma unroll
        for (int mi = 0; mi < 2; mi++)
          o_acc[dj][mi] = __builtin_amdgcn_mfma_f32_16x16x32_bf16(
              av[dj], bp[mi], o_acc[dj][mi], 0, 0, 0);
    }
  }

#pragma unroll
  for (int mi = 0; mi < 2; mi++) {
    float inv = 1.f / l_st[mi];
    int q_idx = qt * 128 + wave * 32 + mi * 16 + ln;
#pragma unroll
    for (int dj = 0; dj < 4; dj++) {
      bf16x4 ov;
#pragma unroll
      for (int r = 0; r < 4; r++) ov[r] = (bf16)(o_acc[dj][mi][r] * inv);
      *(bf16x4*)&O[((size_t)(b * 2048 + q_idx) * 32 + h) * 64 + dj * 16 + qd * 4] = ov;
    }
  }
}

// ---------------------------------------------------------------------------
extern "C" void kernel_launch(void* const* d_in, const int* in_sizes, int n_in,
                              void* d_out, int out_size, void* d_ws,
                              size_t ws_size, hipStream_t stream) {
  const float* x = (const float*)d_in[0];
  const float* fc = (const float*)d_in[1];
  const float* fs = (const float*)d_in[2];
  const float* wq = (const float*)d_in[3];
  const float* wk = (const float*)d_in[4];
  const float* wv = (const float*)d_in[5];
  const float* wo = (const float*)d_in[6];
  float* out = (float*)d_out;

  char* ws = (char*)d_ws;
  const size_t MB = (size_t)1 << 20;
  bf16* xb   = (bf16*)(ws + 0 * MB);   // 16 MB (4096,2048)
  bf16* wqkv = (bf16*)(ws + 16 * MB);  // 12 MB (3072,2048)
  bf16* wob  = (bf16*)(ws + 28 * MB);  // 8 MB
  bf16* Qro  = (bf16*)(ws + 36 * MB);  // 16 MB (B,S,32,64), roped*KAPPA
  bf16* Kro  = (bf16*)(ws + 52 * MB);  // 4 MB  (B,S,8,64), roped
  bf16* Vt   = (bf16*)(ws + 56 * MB);  // 4 MB  (B,8,64,S)
  bf16* Oa   = (bf16*)(ws + 60 * MB);  // 16 MB (B,S,32,64)

  dim3 blk(256);
  f2b_all<<<18432, blk, 0, stream>>>(x, wq, wk, wv, wo, xb, wqkv, wob);
  gemm_qkv<<<dim3(24, 32), blk, 0, stream>>>(xb, wqkv, fc, fs, Qro, Kro, Vt);
  attn_fwd<<<1024, blk, 0, stream>>>(Qro, Kro, Vt, Oa);
  gemm_bt64<float><<<dim3(16, 64), blk, 0, stream>>>(Oa, wob, out, 4096, 2048, 2048);
}

// Round 6
// 310.657 us; speedup vs baseline: 2.0257x; 1.0248x over previous
//
#include <hip/hip_runtime.h>
#include <hip/hip_bf16.h>
#include <type_traits>

typedef __bf16 bf16;
typedef __bf16 bf16x2 __attribute__((ext_vector_type(2)));
typedef __bf16 bf16x4 __attribute__((ext_vector_type(4)));
typedef __bf16 bf16x8 __attribute__((ext_vector_type(8)));
typedef float f32x4 __attribute__((ext_vector_type(4)));

#define AS1 __attribute__((address_space(1)))
#define AS3 __attribute__((address_space(3)))

// 0.125 (1/sqrt(64)) * log2(e): folded into Q so attn scores are log2-domain.
#define KAPPA 0.180336880111f

__device__ __forceinline__ void load_lds16(const void* g, void* l) {
  __builtin_amdgcn_global_load_lds((AS1 void*)g, (AS3 void*)l, 16, 0, 0);
}
__device__ __forceinline__ float exp2_fast(float x) {
  return __builtin_amdgcn_exp2f(x);
}

// ---------------------------------------------------------------------------
// All fp32->bf16 conversions in one launch.
// ---------------------------------------------------------------------------
__global__ void f2b_all(const float* __restrict__ x, const float* __restrict__ wq,
                        const float* __restrict__ wk, const float* __restrict__ wv,
                        const float* __restrict__ wo, bf16* __restrict__ xb,
                        bf16* __restrict__ wqkv, bf16* __restrict__ wob) {
  int bid = blockIdx.x;
  const float* src;
  bf16* dst;
  int off;
  if (bid < 8192) { src = x; dst = xb; off = bid; }
  else if (bid < 12288) { src = wq; dst = wqkv; off = bid - 8192; }
  else if (bid < 13312) { src = wk; dst = wqkv + 4194304; off = bid - 12288; }
  else if (bid < 14336) { src = wv; dst = wqkv + 5242880; off = bid - 13312; }
  else { src = wo; dst = wob; off = bid - 14336; }
  int i = (off * 256 + threadIdx.x) * 4;
  float4 v = *(const float4*)(src + i);
  bf16x4 o = {(bf16)v.x, (bf16)v.y, (bf16)v.z, (bf16)v.w};
  *(bf16x4*)(dst + i) = o;
}

// ---------------------------------------------------------------------------
// Fused QKV projection GEMM: [4096 x 2048] @ [3072 x 2048]^T, 128x128 tile.
// Epilogue: bn<16 Q+rope*KAPPA -> Qro (B,32,S,64); bn<20 K+rope -> Kro
// (B,8,S,64); else V^T -> Vt (B,8,64,S).  Head-major Q/K so attention
// stages contiguous tiles.
// ---------------------------------------------------------------------------
__global__ __launch_bounds__(256) void gemm_qkv(const bf16* __restrict__ A,
                                                const bf16* __restrict__ Bw,
                                                const float* __restrict__ fc,
                                                const float* __restrict__ fs,
                                                bf16* __restrict__ Qro,
                                                bf16* __restrict__ Kro,
                                                bf16* __restrict__ Vt) {
  const int K = 2048;
  __shared__ bf16 As[128][32];
  __shared__ bf16 Bs[128][32];
  const int t = threadIdx.x;
  const int wave = t >> 6, lane = t & 63, qd = lane >> 4, ln = lane & 15;
  const int wm = (wave >> 1) * 64;
  const int wn = (wave & 1) * 64;
  const int bn = blockIdx.x;
  const size_t bm = (size_t)blockIdx.y * 128;

  const bf16* Ab = A + bm * (size_t)K;
  const bf16* Bb = Bw + (size_t)bn * 128 * K;

  f32x4 acc[4][4] = {};

  for (int k0 = 0; k0 < K; k0 += 32) {
#pragma unroll
    for (int i = 0; i < 2; i++) {
      int e = i * 256 + t;
      int ro = e >> 2, gs = (e & 3) ^ (ro & 3);
      load_lds16(Ab + (size_t)ro * K + k0 + gs * 8,
                 (char*)As + i * 4096 + wave * 1024);
      load_lds16(Bb + (size_t)ro * K + k0 + gs * 8,
                 (char*)Bs + i * 4096 + wave * 1024);
    }
    __syncthreads();

    bf16x8 af[4], bfr[4];
#pragma unroll
    for (int i = 0; i < 4; i++) {
      int row = wm + i * 16 + ln;
      af[i] = *(const bf16x8*)((const char*)As + row * 64 + (qd ^ (row & 3)) * 16);
    }
#pragma unroll
    for (int j = 0; j < 4; j++) {
      int row = wn + j * 16 + ln;
      bfr[j] = *(const bf16x8*)((const char*)Bs + row * 64 + (qd ^ (row & 3)) * 16);
    }
#pragma unroll
    for (int i = 0; i < 4; i++)
#pragma unroll
      for (int j = 0; j < 4; j++)
        acc[i][j] = __builtin_amdgcn_mfma_f32_16x16x32_bf16(af[i], bfr[j],
                                                            acc[i][j], 0, 0, 0);
    __syncthreads();
  }

  // ---- epilogue ----
  const int b = (int)(bm >> 11);
  const int sb = (int)(bm & 2047) + wm;
  const bool odd = ln & 1;

  if (bn < 20) {  // Q or K: rope, head-major output
    const bool isQ = bn < 16;
    const float kap = isQ ? KAPPA : 1.0f;
    const int hh = isQ ? (bn * 2 + (wn >> 6)) : ((bn - 16) * 2 + (wn >> 6));
    bf16* dst = isQ ? (Qro + ((size_t)(b * 32 + hh) * 2048) * 64)
                    : (Kro + ((size_t)(b * 8 + hh) * 2048) * 64);
#pragma unroll
    for (int i = 0; i < 4; i++) {
#pragma unroll
      for (int j = 0; j < 4; j++) {
        const int d = j * 16 + ln;
        const int i_f = d >> 1;
#pragma unroll
        for (int r = 0; r < 4; r++) {
          int s = sb + i * 16 + qd * 4 + r;
          float v = acc[i][j][r];
          float p = __shfl_xor(v, 1);
          float cv = fc[s * 32 + i_f] * kap;
          float sv = fs[s * 32 + i_f] * kap;
          float o = odd ? (p * sv + v * cv) : (v * cv - p * sv);
          dst[(size_t)s * 64 + d] = (bf16)o;
        }
      }
    }
  } else {  // V: write transposed (B,8,64,S)
    const int kh = (bn - 20) * 2 + (wn >> 6);
#pragma unroll
    for (int i = 0; i < 4; i++)
#pragma unroll
      for (int j = 0; j < 4; j++) {
        const int d = j * 16 + ln;
        int s = sb + i * 16 + qd * 4;
        bf16x4 ov = {(bf16)acc[i][j][0], (bf16)acc[i][j][1],
                     (bf16)acc[i][j][2], (bf16)acc[i][j][3]};
        *(bf16x4*)&Vt[((size_t)(b * 8 + kh) * 64 + d) * 2048 + s] = ov;
      }
  }
}

// ---------------------------------------------------------------------------
// Output projection GEMM, 64x128 tile (grid 1024 = 4 blocks/CU).
// ---------------------------------------------------------------------------
template <typename OutT>
__global__ __launch_bounds__(256, 4) void gemm_bt64(const bf16* __restrict__ A,
                                                    const bf16* __restrict__ Bw,
                                                    OutT* __restrict__ C,
                                                    int M, int N, int K) {
  __shared__ bf16 As[64][32];
  __shared__ bf16 Bs[128][32];
  const int t = threadIdx.x;
  const int wave = t >> 6, lane = t & 63, qd = lane >> 4, ln = lane & 15;
  const int wm = (wave >> 1) * 32;
  const int wn = (wave & 1) * 64;
  const size_t bm = (size_t)blockIdx.y * 64;
  const size_t bn = (size_t)blockIdx.x * 128;

  const bf16* Ab = A + bm * (size_t)K;
  const bf16* Bb = Bw + bn * (size_t)K;

  f32x4 acc[2][4] = {};

  for (int k0 = 0; k0 < K; k0 += 32) {
    {
      int e = t;
      int ro = e >> 2, gs = (e & 3) ^ (ro & 3);
      load_lds16(Ab + (size_t)ro * K + k0 + gs * 8, (char*)As + wave * 1024);
    }
#pragma unroll
    for (int i = 0; i < 2; i++) {
      int e = i * 256 + t;
      int ro = e >> 2, gs = (e & 3) ^ (ro & 3);
      load_lds16(Bb + (size_t)ro * K + k0 + gs * 8,
                 (char*)Bs + i * 4096 + wave * 1024);
    }
    __syncthreads();

    bf16x8 af[2], bfr[4];
#pragma unroll
    for (int i = 0; i < 2; i++) {
      int row = wm + i * 16 + ln;
      af[i] = *(const bf16x8*)((const char*)As + row * 64 + (qd ^ (row & 3)) * 16);
    }
#pragma unroll
    for (int j = 0; j < 4; j++) {
      int row = wn + j * 16 + ln;
      bfr[j] = *(const bf16x8*)((const char*)Bs + row * 64 + (qd ^ (row & 3)) * 16);
    }
#pragma unroll
    for (int i = 0; i < 2; i++)
#pragma unroll
      for (int j = 0; j < 4; j++)
        acc[i][j] = __builtin_amdgcn_mfma_f32_16x16x32_bf16(af[i], bfr[j],
                                                            acc[i][j], 0, 0, 0);
    __syncthreads();
  }

#pragma unroll
  for (int i = 0; i < 2; i++)
#pragma unroll
    for (int j = 0; j < 4; j++)
#pragma unroll
      for (int r = 0; r < 4; r++) {
        size_t row = bm + wm + i * 16 + qd * 4 + r;
        size_t col = bn + wn + j * 16 + ln;
        C[row * N + col] = (OutT)acc[i][j][r];
      }
}

// ---------------------------------------------------------------------------
// Flash attention, S^T formulation, causal, log2-domain FIXED-POINT softmax:
// softmax is shift-invariant, scores are bounded (|s|<~10), so use constant
// C=16 instead of a running max: p = 2^(s-16). No running max, no alpha
// rescale, l-reduction deferred to the epilogue.
// Q:(B,32,S,64)  K:(B,8,S,64)  Vt:(B,8,64,S)  ->  O:(B,S,32,64)
// ---------------------------------------------------------------------------
__global__ __launch_bounds__(256, 3) void attn_fwd(const bf16* __restrict__ Q,
                                                   const bf16* __restrict__ Kg,
                                                   const bf16* __restrict__ Vg,
                                                   bf16* __restrict__ O) {
  __shared__ bf16 Qs[128][64];
  __shared__ bf16 Ks[64][64];
  __shared__ bf16 Vs[64][64];   // [d][k]
  __shared__ bf16 Ps[128][64];  // [q][k], swizzled
  const int t = threadIdx.x;
  const int wave = t >> 6, lane = t & 63, qd = lane >> 4, ln = lane & 15;
  const int bid = blockIdx.x;
  const int qt = 15 - (bid >> 6);  // longest blocks dispatch first
  const int bh = bid & 63;
  const int b = bh >> 5, h = bh & 31, kh = h >> 2;
  const bf16* Qb = Q + ((size_t)(b * 32 + h) * 2048 + qt * 128) * 64;  // contiguous
  const bf16* Kb = Kg + (size_t)(b * 8 + kh) * 2048 * 64;              // contiguous
  const bf16* Vb = Vg + (size_t)(b * 8 + kh) * 64 * 2048;              // row stride 2048
  char* PsB = (char*)Ps;

#pragma unroll
  for (int i = 0; i < 4; i++) {
    int e = i * 256 + t;
    int row = e >> 3, sg = (e & 7) ^ (row & 7);
    load_lds16(Qb + (size_t)row * 64 + sg * 8, (char*)Qs + i * 4096 + wave * 1024);
  }

  f32x4 o_acc[4][2] = {};
  float l_st[2] = {0.f, 0.f};
  const int q0 = qt * 128 + wave * 32;
  const int nkb = 2 * qt + 2;

  for (int kb = 0; kb < nkb; kb++) {
    __syncthreads();
#pragma unroll
    for (int i = 0; i < 2; i++) {
      int e = i * 256 + t;
      int row = e >> 3, sg = (e & 7) ^ (row & 7);
      load_lds16(Kb + (size_t)(kb * 64 + row) * 64 + sg * 8,
                 (char*)Ks + i * 4096 + wave * 1024);
      load_lds16(Vb + (size_t)row * 2048 + kb * 64 + sg * 8,
                 (char*)Vs + i * 4096 + wave * 1024);
    }
    __syncthreads();

    // S^T = K*Q^T
    f32x4 s_acc[4][2] = {};
#pragma unroll
    for (int kk = 0; kk < 2; kk++) {
      bf16x8 ak[4], bq[2];
#pragma unroll
      for (int j = 0; j < 4; j++) {
        int row = j * 16 + ln;
        int ph = (kk * 4 + qd) ^ (ln & 7);
        ak[j] = *(const bf16x8*)((const char*)Ks + row * 128 + ph * 16);
      }
#pragma unroll
      for (int mi = 0; mi < 2; mi++) {
        int row = wave * 32 + mi * 16 + ln;
        int ph = (kk * 4 + qd) ^ (ln & 7);
        bq[mi] = *(const bf16x8*)((const char*)Qs + row * 128 + ph * 16);
      }
#pragma unroll
      for (int j = 0; j < 4; j++)
#pragma unroll
        for (int mi = 0; mi < 2; mi++)
          s_acc[j][mi] = __builtin_amdgcn_mfma_f32_16x16x32_bf16(
              ak[j], bq[mi], s_acc[j][mi], 0, 0, 0);
    }

    // fixed-point softmax: p = 2^(s-16); masked -> exact 0
    auto smax = [&](auto maskc) {
      constexpr bool MASK = decltype(maskc)::value;
#pragma unroll
      for (int mi = 0; mi < 2; mi++) {
        const int qv = q0 + mi * 16 + ln;
        const int prow = wave * 32 + mi * 16 + ln;
        float rs = 0.f;
#pragma unroll
        for (int j = 0; j < 4; j++) {
          bf16x4 pk;
#pragma unroll
          for (int r = 0; r < 4; r++) {
            float s = s_acc[j][mi][r];
            if (MASK) {
              int k_glob = kb * 64 + j * 16 + qd * 4 + r;
              if (k_glob > qv) s = -1e5f;
            }
            float pv = exp2_fast(s - 16.f);
            rs += pv;
            pk[r] = (bf16)pv;
          }
          int ps = (j * 2 + (qd >> 1)) ^ (ln & 7);
          *(bf16x4*)(PsB + prow * 128 + ps * 16 + (qd & 1) * 8) = pk;
        }
        l_st[mi] += rs;
      }
    };
    if (kb * 64 + 63 > q0) smax(std::true_type{});
    else smax(std::false_type{});

    // O^T += V^T * P^T  (Ps wave-private; lgkmcnt orders write->read)
#pragma unroll
    for (int kk = 0; kk < 2; kk++) {
      bf16x8 av[4], bp[2];
#pragma unroll
      for (int dj = 0; dj < 4; dj++) {
        int row = dj * 16 + ln;
        int ph = (kk * 4 + qd) ^ (ln & 7);
        av[dj] = *(const bf16x8*)((const char*)Vs + row * 128 + ph * 16);
      }
#pragma unroll
      for (int mi = 0; mi < 2; mi++) {
        int prow = wave * 32 + mi * 16 + ln;
        int ph = (kk * 4 + qd) ^ (ln & 7);
        bp[mi] = *(const bf16x8*)(PsB + prow * 128 + ph * 16);
      }
#pragma unroll
      for (int dj = 0; dj < 4; dj++)
#pragma unroll
        for (int mi = 0; mi < 2; mi++)
          o_acc[dj][mi] = __builtin_amdgcn_mfma_f32_16x16x32_bf16(
              av[dj], bp[mi], o_acc[dj][mi], 0, 0, 0);
    }
  }

  // epilogue: reduce l across quads (each quad summed a disjoint k-subset)
#pragma unroll
  for (int mi = 0; mi < 2; mi++) {
    float lt = l_st[mi];
    lt += __shfl_xor(lt, 16);
    lt += __shfl_xor(lt, 32);
    float inv = 1.f / lt;
    int q_idx = qt * 128 + wave * 32 + mi * 16 + ln;
#pragma unroll
    for (int dj = 0; dj < 4; dj++) {
      bf16x4 ov;
#pragma unroll
      for (int r = 0; r < 4; r++) ov[r] = (bf16)(o_acc[dj][mi][r] * inv);
      *(bf16x4*)&O[((size_t)(b * 2048 + q_idx) * 32 + h) * 64 + dj * 16 + qd * 4] = ov;
    }
  }
}

// ---------------------------------------------------------------------------
extern "C" void kernel_launch(void* const* d_in, const int* in_sizes, int n_in,
                              void* d_out, int out_size, void* d_ws,
                              size_t ws_size, hipStream_t stream) {
  const float* x = (const float*)d_in[0];
  const float* fc = (const float*)d_in[1];
  const float* fs = (const float*)d_in[2];
  const float* wq = (const float*)d_in[3];
  const float* wk = (const float*)d_in[4];
  const float* wv = (const float*)d_in[5];
  const float* wo = (const float*)d_in[6];
  float* out = (float*)d_out;

  char* ws = (char*)d_ws;
  const size_t MB = (size_t)1 << 20;
  bf16* xb   = (bf16*)(ws + 0 * MB);   // 16 MB (4096,2048)
  bf16* wqkv = (bf16*)(ws + 16 * MB);  // 12 MB (3072,2048)
  bf16* wob  = (bf16*)(ws + 28 * MB);  // 8 MB
  bf16* Qro  = (bf16*)(ws + 36 * MB);  // 16 MB (B,32,S,64), roped*KAPPA
  bf16* Kro  = (bf16*)(ws + 52 * MB);  // 4 MB  (B,8,S,64), roped
  bf16* Vt   = (bf16*)(ws + 56 * MB);  // 4 MB  (B,8,64,S)
  bf16* Oa   = (bf16*)(ws + 60 * MB);  // 16 MB (B,S,32,64)

  dim3 blk(256);
  f2b_all<<<18432, blk, 0, stream>>>(x, wq, wk, wv, wo, xb, wqkv, wob);
  gemm_qkv<<<dim3(24, 32), blk, 0, stream>>>(xb, wqkv, fc, fs, Qro, Kro, Vt);
  attn_fwd<<<1024, blk, 0, stream>>>(Qro, Kro, Vt, Oa);
  gemm_bt64<float><<<dim3(16, 64), blk, 0, stream>>>(Oa, wob, out, 4096, 2048, 2048);
}

// Round 7
// 306.579 us; speedup vs baseline: 2.0526x; 1.0133x over previous
//
#include <hip/hip_runtime.h>
#include <hip/hip_bf16.h>
#include <type_traits>

typedef __bf16 bf16;
typedef __bf16 bf16x2 __attribute__((ext_vector_type(2)));
typedef __bf16 bf16x4 __attribute__((ext_vector_type(4)));
typedef __bf16 bf16x8 __attribute__((ext_vector_type(8)));
typedef float f32x4 __attribute__((ext_vector_type(4)));

#define AS1 __attribute__((address_space(1)))
#define AS3 __attribute__((address_space(3)))

// 0.125 (1/sqrt(64)) * log2(e): folded into Q so attn scores are log2-domain.
#define KAPPA 0.180336880111f

__device__ __forceinline__ void load_lds16(const void* g, void* l) {
  __builtin_amdgcn_global_load_lds((AS1 void*)g, (AS3 void*)l, 16, 0, 0);
}
__device__ __forceinline__ float exp2_fast(float x) {
  return __builtin_amdgcn_exp2f(x);
}

// ---------------------------------------------------------------------------
// All fp32->bf16 conversions in one launch.
// ---------------------------------------------------------------------------
__global__ void f2b_all(const float* __restrict__ x, const float* __restrict__ wq,
                        const float* __restrict__ wk, const float* __restrict__ wv,
                        const float* __restrict__ wo, bf16* __restrict__ xb,
                        bf16* __restrict__ wqkv, bf16* __restrict__ wob) {
  int bid = blockIdx.x;
  const float* src;
  bf16* dst;
  int off;
  if (bid < 8192) { src = x; dst = xb; off = bid; }
  else if (bid < 12288) { src = wq; dst = wqkv; off = bid - 8192; }
  else if (bid < 13312) { src = wk; dst = wqkv + 4194304; off = bid - 12288; }
  else if (bid < 14336) { src = wv; dst = wqkv + 5242880; off = bid - 13312; }
  else { src = wo; dst = wob; off = bid - 14336; }
  int i = (off * 256 + threadIdx.x) * 4;
  float4 v = *(const float4*)(src + i);
  bf16x4 o = {(bf16)v.x, (bf16)v.y, (bf16)v.z, (bf16)v.w};
  *(bf16x4*)(dst + i) = o;
}

// ---------------------------------------------------------------------------
// Fused QKV projection GEMM: [4096 x 2048] @ [3072 x 2048]^T, 128x128 tile,
// BK=64 (32 iters, 32 MFMA per barrier pair -- halves barrier drains).
// LDS rows are 128B (8 x 16B segs), xor-swizzled seg ^= row&7.
// Epilogue: bn<16 Q+rope*KAPPA -> Qro (B,32,S,64); bn<20 K+rope -> Kro
// (B,8,S,64); else V^T -> Vt (B,8,64,S).
// ---------------------------------------------------------------------------
__global__ __launch_bounds__(256) void gemm_qkv(const bf16* __restrict__ A,
                                                const bf16* __restrict__ Bw,
                                                const float* __restrict__ fc,
                                                const float* __restrict__ fs,
                                                bf16* __restrict__ Qro,
                                                bf16* __restrict__ Kro,
                                                bf16* __restrict__ Vt) {
  const int K = 2048;
  __shared__ bf16 As[128][64];
  __shared__ bf16 Bs[128][64];
  const int t = threadIdx.x;
  const int wave = t >> 6, lane = t & 63, qd = lane >> 4, ln = lane & 15;
  const int wm = (wave >> 1) * 64;
  const int wn = (wave & 1) * 64;
  const int bn = blockIdx.x;
  const size_t bm = (size_t)blockIdx.y * 128;

  const bf16* Ab = A + bm * (size_t)K;
  const bf16* Bb = Bw + (size_t)bn * 128 * K;

  f32x4 acc[4][4] = {};

  for (int k0 = 0; k0 < K; k0 += 64) {
#pragma unroll
    for (int i = 0; i < 4; i++) {
      int e = i * 256 + t;
      int ro = e >> 3, gs = (e & 7) ^ (ro & 7);
      load_lds16(Ab + (size_t)ro * K + k0 + gs * 8,
                 (char*)As + i * 4096 + wave * 1024);
      load_lds16(Bb + (size_t)ro * K + k0 + gs * 8,
                 (char*)Bs + i * 4096 + wave * 1024);
    }
    __syncthreads();

#pragma unroll
    for (int kk = 0; kk < 2; kk++) {
      bf16x8 af[4], bfr[4];
#pragma unroll
      for (int i = 0; i < 4; i++) {
        int row = wm + i * 16 + ln;
        int ps = (kk * 4 + qd) ^ (row & 7);
        af[i] = *(const bf16x8*)((const char*)As + row * 128 + ps * 16);
      }
#pragma unroll
      for (int j = 0; j < 4; j++) {
        int row = wn + j * 16 + ln;
        int ps = (kk * 4 + qd) ^ (row & 7);
        bfr[j] = *(const bf16x8*)((const char*)Bs + row * 128 + ps * 16);
      }
#pragma unroll
      for (int i = 0; i < 4; i++)
#pragma unroll
        for (int j = 0; j < 4; j++)
          acc[i][j] = __builtin_amdgcn_mfma_f32_16x16x32_bf16(af[i], bfr[j],
                                                              acc[i][j], 0, 0, 0);
    }
    __syncthreads();
  }

  // ---- epilogue ----
  const int b = (int)(bm >> 11);
  const int sb = (int)(bm & 2047) + wm;
  const bool odd = ln & 1;

  if (bn < 20) {  // Q or K: rope, head-major output
    const bool isQ = bn < 16;
    const float kap = isQ ? KAPPA : 1.0f;
    const int hh = isQ ? (bn * 2 + (wn >> 6)) : ((bn - 16) * 2 + (wn >> 6));
    bf16* dst = isQ ? (Qro + ((size_t)(b * 32 + hh) * 2048) * 64)
                    : (Kro + ((size_t)(b * 8 + hh) * 2048) * 64);
#pragma unroll
    for (int i = 0; i < 4; i++) {
#pragma unroll
      for (int j = 0; j < 4; j++) {
        const int d = j * 16 + ln;
        const int i_f = d >> 1;
#pragma unroll
        for (int r = 0; r < 4; r++) {
          int s = sb + i * 16 + qd * 4 + r;
          float v = acc[i][j][r];
          float p = __shfl_xor(v, 1);
          float cv = fc[s * 32 + i_f] * kap;
          float sv = fs[s * 32 + i_f] * kap;
          float o = odd ? (p * sv + v * cv) : (v * cv - p * sv);
          dst[(size_t)s * 64 + d] = (bf16)o;
        }
      }
    }
  } else {  // V: write transposed (B,8,64,S)
    const int kh = (bn - 20) * 2 + (wn >> 6);
#pragma unroll
    for (int i = 0; i < 4; i++)
#pragma unroll
      for (int j = 0; j < 4; j++) {
        const int d = j * 16 + ln;
        int s = sb + i * 16 + qd * 4;
        bf16x4 ov = {(bf16)acc[i][j][0], (bf16)acc[i][j][1],
                     (bf16)acc[i][j][2], (bf16)acc[i][j][3]};
        *(bf16x4*)&Vt[((size_t)(b * 8 + kh) * 64 + d) * 2048 + s] = ov;
      }
  }
}

// ---------------------------------------------------------------------------
// Output projection GEMM, 64x128 tile, BK=64, grid 1024 = 4 blocks/CU.
// ---------------------------------------------------------------------------
template <typename OutT>
__global__ __launch_bounds__(256, 4) void gemm_bt64(const bf16* __restrict__ A,
                                                    const bf16* __restrict__ Bw,
                                                    OutT* __restrict__ C,
                                                    int M, int N, int K) {
  __shared__ bf16 As[64][64];    // 8 KB
  __shared__ bf16 Bs[128][64];   // 16 KB
  const int t = threadIdx.x;
  const int wave = t >> 6, lane = t & 63, qd = lane >> 4, ln = lane & 15;
  const int wm = (wave >> 1) * 32;
  const int wn = (wave & 1) * 64;
  const size_t bm = (size_t)blockIdx.y * 64;
  const size_t bn = (size_t)blockIdx.x * 128;

  const bf16* Ab = A + bm * (size_t)K;
  const bf16* Bb = Bw + bn * (size_t)K;

  f32x4 acc[2][4] = {};

  for (int k0 = 0; k0 < K; k0 += 64) {
#pragma unroll
    for (int i = 0; i < 2; i++) {
      int e = i * 256 + t;
      int ro = e >> 3, gs = (e & 7) ^ (ro & 7);
      load_lds16(Ab + (size_t)ro * K + k0 + gs * 8,
                 (char*)As + i * 4096 + wave * 1024);
    }
#pragma unroll
    for (int i = 0; i < 4; i++) {
      int e = i * 256 + t;
      int ro = e >> 3, gs = (e & 7) ^ (ro & 7);
      load_lds16(Bb + (size_t)ro * K + k0 + gs * 8,
                 (char*)Bs + i * 4096 + wave * 1024);
    }
    __syncthreads();

#pragma unroll
    for (int kk = 0; kk < 2; kk++) {
      bf16x8 af[2], bfr[4];
#pragma unroll
      for (int i = 0; i < 2; i++) {
        int row = wm + i * 16 + ln;
        int ps = (kk * 4 + qd) ^ (row & 7);
        af[i] = *(const bf16x8*)((const char*)As + row * 128 + ps * 16);
      }
#pragma unroll
      for (int j = 0; j < 4; j++) {
        int row = wn + j * 16 + ln;
        int ps = (kk * 4 + qd) ^ (row & 7);
        bfr[j] = *(const bf16x8*)((const char*)Bs + row * 128 + ps * 16);
      }
#pragma unroll
      for (int i = 0; i < 2; i++)
#pragma unroll
        for (int j = 0; j < 4; j++)
          acc[i][j] = __builtin_amdgcn_mfma_f32_16x16x32_bf16(af[i], bfr[j],
                                                              acc[i][j], 0, 0, 0);
    }
    __syncthreads();
  }

#pragma unroll
  for (int i = 0; i < 2; i++)
#pragma unroll
    for (int j = 0; j < 4; j++)
#pragma unroll
      for (int r = 0; r < 4; r++) {
        size_t row = bm + wm + i * 16 + qd * 4 + r;
        size_t col = bn + wn + j * 16 + ln;
        C[row * N + col] = (OutT)acc[i][j][r];
      }
}

// ---------------------------------------------------------------------------
// Flash attention, S^T formulation, causal, log2-domain FIXED-POINT softmax:
// p = 2^(s-16) (scores bounded, shift-invariant). No running max/alpha;
// l-reduction deferred to epilogue.
// Q:(B,32,S,64)  K:(B,8,S,64)  Vt:(B,8,64,S)  ->  O:(B,S,32,64)
// ---------------------------------------------------------------------------
__global__ __launch_bounds__(256, 3) void attn_fwd(const bf16* __restrict__ Q,
                                                   const bf16* __restrict__ Kg,
                                                   const bf16* __restrict__ Vg,
                                                   bf16* __restrict__ O) {
  __shared__ bf16 Qs[128][64];
  __shared__ bf16 Ks[64][64];
  __shared__ bf16 Vs[64][64];   // [d][k]
  __shared__ bf16 Ps[128][64];  // [q][k], swizzled
  const int t = threadIdx.x;
  const int wave = t >> 6, lane = t & 63, qd = lane >> 4, ln = lane & 15;
  const int bid = blockIdx.x;
  const int qt = 15 - (bid >> 6);  // longest blocks dispatch first
  const int bh = bid & 63;
  const int b = bh >> 5, h = bh & 31, kh = h >> 2;
  const bf16* Qb = Q + ((size_t)(b * 32 + h) * 2048 + qt * 128) * 64;  // contiguous
  const bf16* Kb = Kg + (size_t)(b * 8 + kh) * 2048 * 64;              // contiguous
  const bf16* Vb = Vg + (size_t)(b * 8 + kh) * 64 * 2048;              // row stride 2048
  char* PsB = (char*)Ps;

#pragma unroll
  for (int i = 0; i < 4; i++) {
    int e = i * 256 + t;
    int row = e >> 3, sg = (e & 7) ^ (row & 7);
    load_lds16(Qb + (size_t)row * 64 + sg * 8, (char*)Qs + i * 4096 + wave * 1024);
  }

  f32x4 o_acc[4][2] = {};
  float l_st[2] = {0.f, 0.f};
  const int q0 = qt * 128 + wave * 32;
  const int nkb = 2 * qt + 2;

  for (int kb = 0; kb < nkb; kb++) {
    __syncthreads();
#pragma unroll
    for (int i = 0; i < 2; i++) {
      int e = i * 256 + t;
      int row = e >> 3, sg = (e & 7) ^ (row & 7);
      load_lds16(Kb + (size_t)(kb * 64 + row) * 64 + sg * 8,
                 (char*)Ks + i * 4096 + wave * 1024);
      load_lds16(Vb + (size_t)row * 2048 + kb * 64 + sg * 8,
                 (char*)Vs + i * 4096 + wave * 1024);
    }
    __syncthreads();

    // S^T = K*Q^T
    f32x4 s_acc[4][2] = {};
#pragma unroll
    for (int kk = 0; kk < 2; kk++) {
      bf16x8 ak[4], bq[2];
#pragma unroll
      for (int j = 0; j < 4; j++) {
        int row = j * 16 + ln;
        int ph = (kk * 4 + qd) ^ (ln & 7);
        ak[j] = *(const bf16x8*)((const char*)Ks + row * 128 + ph * 16);
      }
#pragma unroll
      for (int mi = 0; mi < 2; mi++) {
        int row = wave * 32 + mi * 16 + ln;
        int ph = (kk * 4 + qd) ^ (ln & 7);
        bq[mi] = *(const bf16x8*)((const char*)Qs + row * 128 + ph * 16);
      }
#pragma unroll
      for (int j = 0; j < 4; j++)
#pragma unroll
        for (int mi = 0; mi < 2; mi++)
          s_acc[j][mi] = __builtin_amdgcn_mfma_f32_16x16x32_bf16(
              ak[j], bq[mi], s_acc[j][mi], 0, 0, 0);
    }

    // fixed-point softmax: p = 2^(s-16); masked -> exact 0
    auto smax = [&](auto maskc) {
      constexpr bool MASK = decltype(maskc)::value;
#pragma unroll
      for (int mi = 0; mi < 2; mi++) {
        const int qv = q0 + mi * 16 + ln;
        const int prow = wave * 32 + mi * 16 + ln;
        float rs = 0.f;
#pragma unroll
        for (int j = 0; j < 4; j++) {
          bf16x4 pk;
#pragma unroll
          for (int r = 0; r < 4; r++) {
            float s = s_acc[j][mi][r];
            if (MASK) {
              int k_glob = kb * 64 + j * 16 + qd * 4 + r;
              if (k_glob > qv) s = -1e5f;
            }
            float pv = exp2_fast(s - 16.f);
            rs += pv;
            pk[r] = (bf16)pv;
          }
          int ps = (j * 2 + (qd >> 1)) ^ (ln & 7);
          *(bf16x4*)(PsB + prow * 128 + ps * 16 + (qd & 1) * 8) = pk;
        }
        l_st[mi] += rs;
      }
    };
    if (kb * 64 + 63 > q0) smax(std::true_type{});
    else smax(std::false_type{});

    // O^T += V^T * P^T  (Ps wave-private; lgkmcnt orders write->read)
#pragma unroll
    for (int kk = 0; kk < 2; kk++) {
      bf16x8 av[4], bp[2];
#pragma unroll
      for (int dj = 0; dj < 4; dj++) {
        int row = dj * 16 + ln;
        int ph = (kk * 4 + qd) ^ (ln & 7);
        av[dj] = *(const bf16x8*)((const char*)Vs + row * 128 + ph * 16);
      }
#pragma unroll
      for (int mi = 0; mi < 2; mi++) {
        int prow = wave * 32 + mi * 16 + ln;
        int ph = (kk * 4 + qd) ^ (ln & 7);
        bp[mi] = *(const bf16x8*)(PsB + prow * 128 + ph * 16);
      }
#pragma unroll
      for (int dj = 0; dj < 4; dj++)
#pragma unroll
        for (int mi = 0; mi < 2; mi++)
          o_acc[dj][mi] = __builtin_amdgcn_mfma_f32_16x16x32_bf16(
              av[dj], bp[mi], o_acc[dj][mi], 0, 0, 0);
    }
  }

  // epilogue: reduce l across quads (each quad summed a disjoint k-subset)
#pragma unroll
  for (int mi = 0; mi < 2; mi++) {
    float lt = l_st[mi];
    lt += __shfl_xor(lt, 16);
    lt += __shfl_xor(lt, 32);
    float inv = 1.f / lt;
    int q_idx = qt * 128 + wave * 32 + mi * 16 + ln;
#pragma unroll
    for (int dj = 0; dj < 4; dj++) {
      bf16x4 ov;
#pragma unroll
      for (int r = 0; r < 4; r++) ov[r] = (bf16)(o_acc[dj][mi][r] * inv);
      *(bf16x4*)&O[((size_t)(b * 2048 + q_idx) * 32 + h) * 64 + dj * 16 + qd * 4] = ov;
    }
  }
}

// ---------------------------------------------------------------------------
extern "C" void kernel_launch(void* const* d_in, const int* in_sizes, int n_in,
                              void* d_out, int out_size, void* d_ws,
                              size_t ws_size, hipStream_t stream) {
  const float* x = (const float*)d_in[0];
  const float* fc = (const float*)d_in[1];
  const float* fs = (const float*)d_in[2];
  const float* wq = (const float*)d_in[3];
  const float* wk = (const float*)d_in[4];
  const float* wv = (const float*)d_in[5];
  const float* wo = (const float*)d_in[6];
  float* out = (float*)d_out;

  char* ws = (char*)d_ws;
  const size_t MB = (size_t)1 << 20;
  bf16* xb   = (bf16*)(ws + 0 * MB);   // 16 MB (4096,2048)
  bf16* wqkv = (bf16*)(ws + 16 * MB);  // 12 MB (3072,2048)
  bf16* wob  = (bf16*)(ws + 28 * MB);  // 8 MB
  bf16* Qro  = (bf16*)(ws + 36 * MB);  // 16 MB (B,32,S,64), roped*KAPPA
  bf16* Kro  = (bf16*)(ws + 52 * MB);  // 4 MB  (B,8,S,64), roped
  bf16* Vt   = (bf16*)(ws + 56 * MB);  // 4 MB  (B,8,64,S)
  bf16* Oa   = (bf16*)(ws + 60 * MB);  // 16 MB (B,S,32,64)

  dim3 blk(256);
  f2b_all<<<18432, blk, 0, stream>>>(x, wq, wk, wv, wo, xb, wqkv, wob);
  gemm_qkv<<<dim3(24, 32), blk, 0, stream>>>(xb, wqkv, fc, fs, Qro, Kro, Vt);
  attn_fwd<<<1024, blk, 0, stream>>>(Qro, Kro, Vt, Oa);
  gemm_bt64<float><<<dim3(16, 64), blk, 0, stream>>>(Oa, wob, out, 4096, 2048, 2048);
}